// Round 1
// baseline (897.954 us; speedup 1.0000x reference)
//
#include <hip/hip_runtime.h>
#include <hip/hip_bf16.h>

// Problem constants: T=512, B=8, D=512, H=8, DH=64
#define TT 512
#define BB 8
#define DD 512
#define HH 8
#define DHH 64
#define NR 1023            // distinct relative distances: -511..511

// ---------------------------------------------------------------------------
// Kernel 1: sinusoid feature table  feat[r, c], r in [0,1023), c in [0,512)
//   dist = r - 511; half = 256
//   c <  256: sin(dist * freq[c])
//   c >= 256: cos(dist * freq[c-256]),  freq[c] = exp(-log(1e4)*c/256)
// ---------------------------------------------------------------------------
__global__ __launch_bounds__(256) void feat_kernel(float* __restrict__ feat) {
    int idx = blockIdx.x * 256 + threadIdx.x;
    if (idx >= NR * DD) return;
    int r = idx >> 9;          // / 512
    int c = idx & 511;
    float dist = (float)(r - 511);
    int cc = c & 255;
    float freq = expf((-logf(10000.0f) * (float)cc) / 256.0f);
    float ang = dist * freq;
    feat[idx] = (c < 256) ? sinf(ang) : cosf(ang);
}

// ---------------------------------------------------------------------------
// Kernel 2: generic fp32 GEMM  C[M,N] = A[M,K] @ B[K,N] (+ bias)
// 64x64 tile, BK=16, 256 threads, 4x4 microtile per thread.
// ---------------------------------------------------------------------------
#define BM 64
#define BN 64
#define BK 16

__global__ __launch_bounds__(256) void gemm_kernel(
        const float* __restrict__ A, const float* __restrict__ B,
        const float* __restrict__ bias, float* __restrict__ C,
        int M, int N, int K) {
    __shared__ __align__(16) float As[BM][BK + 1];   // stride 17: conflict-free
    __shared__ __align__(16) float Bs[BK][BN + 4];   // stride 68: f4-aligned rows

    int tid = threadIdx.x;
    int tx = tid & 15;     // n microtile
    int ty = tid >> 4;     // m microtile
    int m0 = blockIdx.y * BM;
    int n0 = blockIdx.x * BN;

    float acc[4][4] = {};

    for (int k0 = 0; k0 < K; k0 += BK) {
        #pragma unroll
        for (int l = 0; l < 4; ++l) {
            int idx = tid + l * 256;           // 64x16 A tile
            int r = idx >> 4, c = idx & 15;
            int gr = m0 + r;
            As[r][c] = (gr < M) ? A[(size_t)gr * K + (k0 + c)] : 0.0f;
        }
        #pragma unroll
        for (int l = 0; l < 4; ++l) {
            int idx = tid + l * 256;           // 16x64 B tile
            int c = idx & 63, r = idx >> 6;
            Bs[r][c] = B[(size_t)(k0 + r) * N + (n0 + c)];
        }
        __syncthreads();

        #pragma unroll
        for (int kk = 0; kk < BK; ++kk) {
            float a[4];
            #pragma unroll
            for (int i = 0; i < 4; ++i) a[i] = As[ty * 4 + i][kk];
            float4 bv = *(const float4*)&Bs[kk][tx * 4];
            float b[4] = {bv.x, bv.y, bv.z, bv.w};
            #pragma unroll
            for (int i = 0; i < 4; ++i)
                #pragma unroll
                for (int j = 0; j < 4; ++j)
                    acc[i][j] += a[i] * b[j];
        }
        __syncthreads();
    }

    #pragma unroll
    for (int i = 0; i < 4; ++i) {
        int gm = m0 + ty * 4 + i;
        if (gm >= M) continue;
        #pragma unroll
        for (int j = 0; j < 4; ++j) {
            int gn = n0 + tx * 4 + j;
            float v = acc[i][j];
            if (bias) v += bias[gn];
            C[(size_t)gm * N + gn] = v;
        }
    }
}

// ---------------------------------------------------------------------------
// Kernel 3: pv[r,h] = sum_d pos_v[h,d] * table[r, h*64+d]
// ---------------------------------------------------------------------------
__global__ __launch_bounds__(256) void pv_kernel(
        const float* __restrict__ pos_v, const float* __restrict__ table,
        float* __restrict__ pv) {
    int idx = blockIdx.x * 256 + threadIdx.x;
    if (idx >= NR * HH) return;
    int r = idx >> 3, h = idx & 7;
    const float* trow = table + (size_t)r * DD + h * DHH;
    const float* vrow = pos_v + h * DHH;
    float s = 0.0f;
    #pragma unroll 8
    for (int d = 0; d < DHH; ++d) s += vrow[d] * trow[d];
    pv[idx] = s;
}

// ---------------------------------------------------------------------------
// Kernel 4: fused attention.
// Block = (i-tile of 8 rows, b, h). 256 threads = 4 waves.
// energy[i,j] = (q_i.k_j + q_i.P[i-j+511] + u.k_j + pv[i-j+511,h]) * scale
//   diag -> -FLT_MAX, then * exp(log_tau); softmax over j; O = attn @ V.
// qkv layout: row (t*B+b) of 1536: [q(512) | k(512) | v(512)], head h at h*64.
// ---------------------------------------------------------------------------
#define TI 8
#define PB (TI + 64 - 1)   // 71 rows of P band per (i-tile, j-tile)

__global__ __launch_bounds__(256) void attn_kernel(
        const float* __restrict__ qkv, const float* __restrict__ table,
        const float* __restrict__ pv, const float* __restrict__ pos_u,
        const float* __restrict__ tau, float* __restrict__ outp) {
    const int i0 = blockIdx.x * TI;
    const int b  = blockIdx.y;
    const int h  = blockIdx.z;
    const int tid = threadIdx.x;

    const float tauexp = expf(tau[0]);
    const float scale = 0.125f;              // 64^-0.5
    const float NEGMAX = -3.4028234663852886e38f;

    __shared__ float q_s[TI][65];
    __shared__ float K_s[64][65];            // K tile, later reused for V tile
    __shared__ float P_s[PB][65];
    __shared__ float E_s[TI * 516];          // energy rows, stride 516
    __shared__ float u_s[DHH];
    __shared__ float pv_s[PB + 1];
    __shared__ float red[TI][33];
    __shared__ float mx_s[TI], sm_s[TI];

    // stage q tile and u
    for (int idx = tid; idx < TI * DHH; idx += 256) {
        int ii = idx >> 6, d = idx & 63;
        q_s[ii][d] = qkv[((size_t)(i0 + ii) * BB + b) * (3 * DD) + h * DHH + d];
    }
    if (tid < DHH) u_s[tid] = pos_u[h * DHH + tid];

    const int jj = tid & 63;
    const int w  = tid >> 6;                 // wave id, rows ii = w*2 + {0,1}

    // ---- pass 1: energy ----
    for (int jt = 0; jt < TT / 64; ++jt) {
        int j0 = jt * 64;
        int rlo = i0 - j0 + 448;             // lowest P row needed (>= 0)
        __syncthreads();                     // previous-iter readers done
        for (int idx = tid; idx < 64 * DHH; idx += 256) {
            int jl = idx >> 6, d = idx & 63;
            K_s[jl][d] = qkv[((size_t)(j0 + jl) * BB + b) * (3 * DD) + DD + h * DHH + d];
        }
        for (int idx = tid; idx < PB * DHH; idx += 256) {
            int r = idx >> 6, d = idx & 63;
            P_s[r][d] = table[(size_t)(rlo + r) * DD + h * DHH + d];
        }
        for (int idx = tid; idx < PB; idx += 256)
            pv_s[idx] = pv[(size_t)(rlo + idx) * HH + h];
        __syncthreads();

        float accA[2] = {0.f, 0.f}, accB[2] = {0.f, 0.f}, accU = 0.f;
        #pragma unroll 4
        for (int d = 0; d < DHH; ++d) {
            float kv = K_s[jj][d];
            accU += u_s[d] * kv;
            #pragma unroll
            for (int q = 0; q < 2; ++q) {
                int ii = (w << 1) + q;
                float qv = q_s[ii][d];
                accA[q] += qv * kv;
                accB[q] += qv * P_s[ii - jj + 63][d];
            }
        }
        #pragma unroll
        for (int q = 0; q < 2; ++q) {
            int ii = (w << 1) + q;
            float e = (accA[q] + accB[q] + accU + pv_s[ii - jj + 63]) * scale;
            if (i0 + ii == j0 + jj) e = NEGMAX;
            e *= tauexp;
            E_s[ii * 516 + j0 + jj] = e;
        }
    }
    __syncthreads();

    // ---- pass 2: softmax stats (8 rows x 32 threads) ----
    {
        int g = tid >> 5, l = tid & 31;
        float m = NEGMAX;
        for (int j = l; j < TT; j += 32) m = fmaxf(m, E_s[g * 516 + j]);
        red[g][l] = m;
        __syncthreads();
        if (l == 0) {
            float mm = red[g][0];
            for (int t2 = 1; t2 < 32; ++t2) mm = fmaxf(mm, red[g][t2]);
            mx_s[g] = mm;
        }
        __syncthreads();
        float mm = mx_s[g];
        float s = 0.0f;
        for (int j = l; j < TT; j += 32) {
            float ev = __expf(E_s[g * 516 + j] - mm);
            E_s[g * 516 + j] = ev;
            s += ev;
        }
        red[g][l] = s;
        __syncthreads();
        if (l == 0) {
            float ss = 0.0f;
            for (int t2 = 0; t2 < 32; ++t2) ss += red[g][t2];
            sm_s[g] = ss;
        }
    }

    // ---- pass 3: O = attn @ V ----
    const int dl = tid & 63;
    float o[2] = {0.f, 0.f};
    for (int jt = 0; jt < TT / 64; ++jt) {
        int j0 = jt * 64;
        __syncthreads();
        for (int idx = tid; idx < 64 * DHH; idx += 256) {
            int jl = idx >> 6, d = idx & 63;
            K_s[jl][d] = qkv[((size_t)(j0 + jl) * BB + b) * (3 * DD) + 2 * DD + h * DHH + d];
        }
        __syncthreads();
        for (int jl = 0; jl < 64; ++jl) {
            float vv = K_s[jl][dl];
            #pragma unroll
            for (int q = 0; q < 2; ++q)
                o[q] += E_s[((w << 1) + q) * 516 + j0 + jl] * vv;
        }
    }
    #pragma unroll
    for (int q = 0; q < 2; ++q) {
        int ii = (w << 1) + q;
        float val = o[q] / sm_s[ii];
        outp[((size_t)(i0 + ii) * BB + b) * DD + h * DHH + dl] = val;
    }
}

// ---------------------------------------------------------------------------
// launch
// ---------------------------------------------------------------------------
extern "C" void kernel_launch(void* const* d_in, const int* in_sizes, int n_in,
                              void* d_out, int out_size, void* d_ws, size_t ws_size,
                              hipStream_t stream) {
    const float* x     = (const float*)d_in[0];   // (512, 8, 512)
    const float* W_qkv = (const float*)d_in[1];   // (512, 1536)
    const float* W_pos = (const float*)d_in[2];   // (512, 512)
    const float* pos_u = (const float*)d_in[3];   // (8, 64)
    const float* pos_v = (const float*)d_in[4];   // (8, 64)
    const float* W_out = (const float*)d_in[5];   // (512, 512)
    const float* b_out = (const float*)d_in[6];   // (512,)
    const float* tau   = (const float*)d_in[7];   // (1,)
    float* out = (float*)d_out;                   // (512, 8, 512)

    float* ws    = (float*)d_ws;
    float* feat  = ws;                            // 1023*512
    float* table = feat + (size_t)NR * DD;        // 1023*512
    float* pv    = table + (size_t)NR * DD;       // 1023*8
    float* qkvb  = pv + (size_t)NR * HH;          // 4096*1536
    float* attno = qkvb + (size_t)(TT * BB) * (3 * DD);  // 4096*512
    // total ~38 MB of workspace

    // 1. sinusoid features
    feat_kernel<<<(NR * DD + 255) / 256, 256, 0, stream>>>(feat);
    // 2. table = feat @ W_pos   (1023 x 512 x 512)
    gemm_kernel<<<dim3(DD / BN, (NR + BM - 1) / BM), 256, 0, stream>>>(
        feat, W_pos, nullptr, table, NR, DD, DD);
    // 3. pv[r,h]
    pv_kernel<<<(NR * HH + 255) / 256, 256, 0, stream>>>(pos_v, table, pv);
    // 4. qkv = x @ W_qkv   (4096 x 1536 x 512)
    gemm_kernel<<<dim3((3 * DD) / BN, (TT * BB) / BM), 256, 0, stream>>>(
        x, W_qkv, nullptr, qkvb, TT * BB, 3 * DD, DD);
    // 5. fused attention -> attno (4096 x 512)
    attn_kernel<<<dim3(TT / TI, BB, HH), 256, 0, stream>>>(
        qkvb, table, pv, pos_u, tau, attno);
    // 6. out = attno @ W_out + b_out   (4096 x 512 x 512)
    gemm_kernel<<<dim3(DD / BN, (TT * BB) / BM), 256, 0, stream>>>(
        attno, W_out, b_out, out, TT * BB, DD, DD);
}

// Round 2
// 872.079 us; speedup vs baseline: 1.0297x; 1.0297x over previous
//
#include <hip/hip_runtime.h>
#include <hip/hip_bf16.h>

// Problem constants: T=512, B=8, D=512, H=8, DH=64
#define TT 512
#define BB 8
#define DD 512
#define HH 8
#define DHH 64
#define NR 1023            // distinct relative distances: -511..511

// ---------------------------------------------------------------------------
// Kernel 1: sinusoid feature table  feat[r, c], r in [0,1023), c in [0,512)
// ---------------------------------------------------------------------------
__global__ __launch_bounds__(256) void feat_kernel(float* __restrict__ feat) {
    int idx = blockIdx.x * 256 + threadIdx.x;
    if (idx >= NR * DD) return;
    int r = idx >> 9;          // / 512
    int c = idx & 511;
    float dist = (float)(r - 511);
    int cc = c & 255;
    float freq = expf((-logf(10000.0f) * (float)cc) / 256.0f);
    float ang = dist * freq;
    feat[idx] = (c < 256) ? sinf(ang) : cosf(ang);
}

// ---------------------------------------------------------------------------
// Kernel 2: generic fp32 GEMM  C[M,N] = A[M,K] @ B[K,N] (+ bias)
// 64x64 tile, BK=16, 256 threads, 4x4 microtile per thread.
// ---------------------------------------------------------------------------
#define BM 64
#define BN 64
#define BK 16

__global__ __launch_bounds__(256) void gemm_kernel(
        const float* __restrict__ A, const float* __restrict__ B,
        const float* __restrict__ bias, float* __restrict__ C,
        int M, int N, int K) {
    __shared__ __align__(16) float As[BM][BK + 1];   // stride 17: conflict-free
    __shared__ __align__(16) float Bs[BK][BN + 4];   // stride 68: f4-aligned rows

    int tid = threadIdx.x;
    int tx = tid & 15;     // n microtile
    int ty = tid >> 4;     // m microtile
    int m0 = blockIdx.y * BM;
    int n0 = blockIdx.x * BN;

    float acc[4][4] = {};

    for (int k0 = 0; k0 < K; k0 += BK) {
        #pragma unroll
        for (int l = 0; l < 4; ++l) {
            int idx = tid + l * 256;           // 64x16 A tile
            int r = idx >> 4, c = idx & 15;
            int gr = m0 + r;
            As[r][c] = (gr < M) ? A[(size_t)gr * K + (k0 + c)] : 0.0f;
        }
        #pragma unroll
        for (int l = 0; l < 4; ++l) {
            int idx = tid + l * 256;           // 16x64 B tile
            int c = idx & 63, r = idx >> 6;
            Bs[r][c] = B[(size_t)(k0 + r) * N + (n0 + c)];
        }
        __syncthreads();

        #pragma unroll
        for (int kk = 0; kk < BK; ++kk) {
            float a[4];
            #pragma unroll
            for (int i = 0; i < 4; ++i) a[i] = As[ty * 4 + i][kk];
            float4 bv = *(const float4*)&Bs[kk][tx * 4];
            float b[4] = {bv.x, bv.y, bv.z, bv.w};
            #pragma unroll
            for (int i = 0; i < 4; ++i)
                #pragma unroll
                for (int j = 0; j < 4; ++j)
                    acc[i][j] += a[i] * b[j];
        }
        __syncthreads();
    }

    #pragma unroll
    for (int i = 0; i < 4; ++i) {
        int gm = m0 + ty * 4 + i;
        if (gm >= M) continue;
        #pragma unroll
        for (int j = 0; j < 4; ++j) {
            int gn = n0 + tx * 4 + j;
            float v = acc[i][j];
            if (bias) v += bias[gn];
            C[(size_t)gm * N + gn] = v;
        }
    }
}

// ---------------------------------------------------------------------------
// Kernel 3: pv[r,h] = sum_d pos_v[h,d] * table[r, h*64+d]
// ---------------------------------------------------------------------------
__global__ __launch_bounds__(256) void pv_kernel(
        const float* __restrict__ pos_v, const float* __restrict__ table,
        float* __restrict__ pv) {
    int idx = blockIdx.x * 256 + threadIdx.x;
    if (idx >= NR * HH) return;
    int r = idx >> 3, h = idx & 7;
    const float* trow = table + (size_t)r * DD + h * DHH;
    const float* vrow = pos_v + h * DHH;
    float s = 0.0f;
    #pragma unroll 8
    for (int d = 0; d < DHH; ++d) s += vrow[d] * trow[d];
    pv[idx] = s;
}

// ---------------------------------------------------------------------------
// Kernel 4: fused flash-style attention.
// Block = (i-tile of 16 rows, b, h). 256 threads = 4 waves; wave w owns
// i-rows w*4 .. w*4+3. Online softmax: per-row m/l/alpha kept wave-uniform
// in registers (64-lane shuffle reductions, no cross-wave traffic).
//
// Phase A (lane=jj): e[i,j] = (q.k + q.P[i-j] + u.k + pv[i-j]) * scale,
//   diag -> -FLT_MAX, * exp(tau); update m/l; p -> E_s.
// Phase B (lane=d):  o = o*alpha + E_s @ V_s.
// All LDS rows padded to 68 floats (17 quads, odd) -> conflict-free b128.
// LDS total = 47.0 KB -> 3 blocks/CU.
// ---------------------------------------------------------------------------
#define TIF 16

__global__ __launch_bounds__(256, 3) void attn_kernel(
        const float* __restrict__ qkv, const float* __restrict__ table,
        const float* __restrict__ pvt, const float* __restrict__ pos_u,
        const float* __restrict__ tau, float* __restrict__ outp) {
    const int i0 = blockIdx.x * TIF;
    const int b  = blockIdx.y;
    const int h  = blockIdx.z;
    const int tid = threadIdx.x;
    const int lane = tid & 63;
    const int w = tid >> 6;

    const float tauexp = expf(tau[0]);
    const float scale = 0.125f;              // 64^-0.5
    const float NEGMAX = -3.4028234663852886e38f;

    __shared__ __align__(16) float q_s[TIF][68];
    __shared__ __align__(16) float KV_s[64][68];   // K in phase A, V in phase B
    __shared__ __align__(16) float P_s[79][68];    // P band rows
    __shared__ __align__(16) float E_s[TIF][68];   // p values for this j-tile
    __shared__ __align__(16) float u_s[64];
    __shared__ float pv_s[80];

    // stage q (persistent across j-tiles): 16 rows x 16 quads = 256 threads
    {
        int r = tid >> 4, cq = tid & 15;
        const float* src = qkv + ((size_t)(i0 + r) * BB + b) * (3 * DD) + h * DHH + cq * 4;
        *(float4*)&q_s[r][cq * 4] = *(const float4*)src;
    }
    if (tid < 16)
        *(float4*)&u_s[tid * 4] = *(const float4*)(pos_u + h * DHH + tid * 4);

    float m_r[4], l_r[4], o_r[4];
    #pragma unroll
    for (int q = 0; q < 4; ++q) { m_r[q] = NEGMAX; l_r[q] = 0.f; o_r[q] = 0.f; }

    for (int jt = 0; jt < TT / 64; ++jt) {
        const int j0 = jt * 64;
        const int rlo = i0 - j0 + 448;       // P row for (ii=0, jj=63)

        __syncthreads();                     // prev-iter readers of KV_s/E_s done
        // stage K tile: 64 rows x 16 quads
        #pragma unroll
        for (int l4 = 0; l4 < 4; ++l4) {
            int idx = tid + l4 * 256;
            int r = idx >> 4, cq = idx & 15;
            const float* src = qkv + ((size_t)(j0 + r) * BB + b) * (3 * DD) + DD + h * DHH + cq * 4;
            *(float4*)&KV_s[r][cq * 4] = *(const float4*)src;
        }
        // stage P band: 79 rows x 16 quads
        for (int idx = tid; idx < 79 * 16; idx += 256) {
            int r = idx >> 4, cq = idx & 15;
            const float* src = table + (size_t)(rlo + r) * DD + h * DHH + cq * 4;
            *(float4*)&P_s[r][cq * 4] = *(const float4*)src;
        }
        for (int idx = tid; idx < 79; idx += 256)
            pv_s[idx] = pvt[(size_t)(rlo + idx) * HH + h];
        __syncthreads();

        // ---- phase A: energy for 4 rows, lane = jj ----
        float accA[4] = {0.f, 0.f, 0.f, 0.f};
        float accB[4] = {0.f, 0.f, 0.f, 0.f};
        float accU = 0.f;
        #pragma unroll
        for (int cq = 0; cq < 16; ++cq) {
            float4 kv = *(const float4*)&KV_s[lane][cq * 4];
            float4 uv = *(const float4*)&u_s[cq * 4];
            accU += uv.x * kv.x + uv.y * kv.y + uv.z * kv.z + uv.w * kv.w;
            #pragma unroll
            for (int q = 0; q < 4; ++q) {
                int ii = w * 4 + q;
                float4 qv = *(const float4*)&q_s[ii][cq * 4];
                float4 pb = *(const float4*)&P_s[ii - lane + 63][cq * 4];
                accA[q] += qv.x * kv.x + qv.y * kv.y + qv.z * kv.z + qv.w * kv.w;
                accB[q] += qv.x * pb.x + qv.y * pb.y + qv.z * pb.z + qv.w * pb.w;
            }
        }

        float alpha[4];
        #pragma unroll
        for (int q = 0; q < 4; ++q) {
            int ii = w * 4 + q;
            float e = (accA[q] + accB[q] + accU + pv_s[ii - lane + 63]) * scale;
            if (i0 + ii == j0 + lane) e = NEGMAX;
            e *= tauexp;
            float mx = e;
            #pragma unroll
            for (int s = 32; s; s >>= 1) mx = fmaxf(mx, __shfl_xor(mx, s));
            float mn = fmaxf(m_r[q], mx);
            float p = __expf(e - mn);
            float ts = p;
            #pragma unroll
            for (int s = 32; s; s >>= 1) ts += __shfl_xor(ts, s);
            alpha[q] = __expf(m_r[q] - mn);
            l_r[q] = l_r[q] * alpha[q] + ts;
            m_r[q] = mn;
            E_s[ii][lane] = p;
        }
        __syncthreads();                     // K reads + E writes done

        // stage V tile into KV_s (K no longer needed)
        #pragma unroll
        for (int l4 = 0; l4 < 4; ++l4) {
            int idx = tid + l4 * 256;
            int r = idx >> 4, cq = idx & 15;
            const float* src = qkv + ((size_t)(j0 + r) * BB + b) * (3 * DD) + 2 * DD + h * DHH + cq * 4;
            *(float4*)&KV_s[r][cq * 4] = *(const float4*)src;
        }
        __syncthreads();

        // ---- phase B: O update, lane = d ----
        #pragma unroll
        for (int q = 0; q < 4; ++q) o_r[q] *= alpha[q];
        #pragma unroll 4
        for (int jl = 0; jl < 64; jl += 4) {
            float4 e0 = *(const float4*)&E_s[w * 4 + 0][jl];
            float4 e1 = *(const float4*)&E_s[w * 4 + 1][jl];
            float4 e2 = *(const float4*)&E_s[w * 4 + 2][jl];
            float4 e3 = *(const float4*)&E_s[w * 4 + 3][jl];
            float v0 = KV_s[jl + 0][lane];
            float v1 = KV_s[jl + 1][lane];
            float v2 = KV_s[jl + 2][lane];
            float v3 = KV_s[jl + 3][lane];
            o_r[0] += e0.x * v0 + e0.y * v1 + e0.z * v2 + e0.w * v3;
            o_r[1] += e1.x * v0 + e1.y * v1 + e1.z * v2 + e1.w * v3;
            o_r[2] += e2.x * v0 + e2.y * v1 + e2.z * v2 + e2.w * v3;
            o_r[3] += e3.x * v0 + e3.y * v1 + e3.z * v2 + e3.w * v3;
        }
    }

    // epilogue: normalize and write
    #pragma unroll
    for (int q = 0; q < 4; ++q) {
        int ii = w * 4 + q;
        outp[((size_t)(i0 + ii) * BB + b) * DD + h * DHH + lane] = o_r[q] / l_r[q];
    }
}

// ---------------------------------------------------------------------------
// launch
// ---------------------------------------------------------------------------
extern "C" void kernel_launch(void* const* d_in, const int* in_sizes, int n_in,
                              void* d_out, int out_size, void* d_ws, size_t ws_size,
                              hipStream_t stream) {
    const float* x     = (const float*)d_in[0];   // (512, 8, 512)
    const float* W_qkv = (const float*)d_in[1];   // (512, 1536)
    const float* W_pos = (const float*)d_in[2];   // (512, 512)
    const float* pos_u = (const float*)d_in[3];   // (8, 64)
    const float* pos_v = (const float*)d_in[4];   // (8, 64)
    const float* W_out = (const float*)d_in[5];   // (512, 512)
    const float* b_out = (const float*)d_in[6];   // (512,)
    const float* tau   = (const float*)d_in[7];   // (1,)
    float* out = (float*)d_out;                   // (512, 8, 512)

    float* ws    = (float*)d_ws;
    float* feat  = ws;                            // 1023*512
    float* table = feat + (size_t)NR * DD;        // 1023*512
    float* pv    = table + (size_t)NR * DD;       // 1023*8
    float* qkvb  = pv + (size_t)NR * HH;          // 4096*1536
    float* attno = qkvb + (size_t)(TT * BB) * (3 * DD);  // 4096*512

    // 1. sinusoid features
    feat_kernel<<<(NR * DD + 255) / 256, 256, 0, stream>>>(feat);
    // 2. table = feat @ W_pos   (1023 x 512 x 512)
    gemm_kernel<<<dim3(DD / BN, (NR + BM - 1) / BM), 256, 0, stream>>>(
        feat, W_pos, nullptr, table, NR, DD, DD);
    // 3. pv[r,h]
    pv_kernel<<<(NR * HH + 255) / 256, 256, 0, stream>>>(pos_v, table, pv);
    // 4. qkv = x @ W_qkv   (4096 x 1536 x 512)
    gemm_kernel<<<dim3((3 * DD) / BN, (TT * BB) / BM), 256, 0, stream>>>(
        x, W_qkv, nullptr, qkvb, TT * BB, 3 * DD, DD);
    // 5. fused flash attention -> attno (4096 x 512)
    attn_kernel<<<dim3(TT / TIF, BB, HH), 256, 0, stream>>>(
        qkvb, table, pv, pos_u, tau, attno);
    // 6. out = attno @ W_out + b_out   (4096 x 512 x 512)
    gemm_kernel<<<dim3(DD / BN, (TT * BB) / BM), 256, 0, stream>>>(
        attno, W_out, b_out, out, TT * BB, DD, DD);
}

// Round 3
// 341.174 us; speedup vs baseline: 2.6320x; 2.5561x over previous
//
#include <hip/hip_runtime.h>
#include <hip/hip_bf16.h>

// Problem constants: T=512, B=8, D=512, H=8, DH=64
#define TT 512
#define BB 8
#define DD 512
#define HH 8
#define DHH 64
#define NR 1023            // distinct relative distances: -511..511

typedef unsigned short ushort_t;
using frag16 = __attribute__((ext_vector_type(8))) short;   // 8 bf16 (4 VGPRs)
using f32x4  = __attribute__((ext_vector_type(4))) float;   // MFMA accumulator

#define MFMA16 __builtin_amdgcn_mfma_f32_16x16x32_bf16

__device__ inline ushort_t f2bf(float x) {
    __hip_bfloat16 h = __float2bfloat16(x);
    ushort_t u; __builtin_memcpy(&u, &h, 2); return u;
}
__device__ inline float bf2f(ushort_t u) {
    __hip_bfloat16 h; __builtin_memcpy(&h, &u, 2);
    return __bfloat162float(h);
}

// split 8 consecutive floats into hi/lo bf16 and store as 16B vectors
__device__ inline void split_store8(const float* src, ushort_t* dh, ushort_t* dl) {
    union { frag16 v; ushort_t s[8]; } H, L;
    #pragma unroll
    for (int t = 0; t < 8; ++t) {
        float x = src[t];
        ushort_t hh = f2bf(x);
        H.s[t] = hh;
        L.s[t] = f2bf(x - bf2f(hh));
    }
    *(frag16*)dh = H.v;
    *(frag16*)dl = L.v;
}

// ---------------------------------------------------------------------------
// Kernel 1: sinusoid feature table  feat[r, c]
// ---------------------------------------------------------------------------
__global__ __launch_bounds__(256) void feat_kernel(float* __restrict__ feat) {
    int idx = blockIdx.x * 256 + threadIdx.x;
    if (idx >= NR * DD) return;
    int r = idx >> 9;          // / 512
    int c = idx & 511;
    float dist = (float)(r - 511);
    int cc = c & 255;
    float freq = expf((-logf(10000.0f) * (float)cc) / 256.0f);
    float ang = dist * freq;
    feat[idx] = (c < 256) ? sinf(ang) : cosf(ang);
}

// ---------------------------------------------------------------------------
// Kernel 2: generic fp32 GEMM  C[M,N] = A[M,K] @ B[K,N] (+ bias)
// ---------------------------------------------------------------------------
#define BM 64
#define BN 64
#define BK 16

__global__ __launch_bounds__(256) void gemm_kernel(
        const float* __restrict__ A, const float* __restrict__ B,
        const float* __restrict__ bias, float* __restrict__ C,
        int M, int N, int K) {
    __shared__ __align__(16) float As[BM][BK + 1];
    __shared__ __align__(16) float Bs[BK][BN + 4];

    int tid = threadIdx.x;
    int tx = tid & 15;
    int ty = tid >> 4;
    int m0 = blockIdx.y * BM;
    int n0 = blockIdx.x * BN;

    float acc[4][4] = {};

    for (int k0 = 0; k0 < K; k0 += BK) {
        #pragma unroll
        for (int l = 0; l < 4; ++l) {
            int idx = tid + l * 256;
            int r = idx >> 4, c = idx & 15;
            int gr = m0 + r;
            As[r][c] = (gr < M) ? A[(size_t)gr * K + (k0 + c)] : 0.0f;
        }
        #pragma unroll
        for (int l = 0; l < 4; ++l) {
            int idx = tid + l * 256;
            int c = idx & 63, r = idx >> 6;
            Bs[r][c] = B[(size_t)(k0 + r) * N + (n0 + c)];
        }
        __syncthreads();

        #pragma unroll
        for (int kk = 0; kk < BK; ++kk) {
            float a[4];
            #pragma unroll
            for (int i = 0; i < 4; ++i) a[i] = As[ty * 4 + i][kk];
            float4 bv = *(const float4*)&Bs[kk][tx * 4];
            float b[4] = {bv.x, bv.y, bv.z, bv.w};
            #pragma unroll
            for (int i = 0; i < 4; ++i)
                #pragma unroll
                for (int j = 0; j < 4; ++j)
                    acc[i][j] += a[i] * b[j];
        }
        __syncthreads();
    }

    #pragma unroll
    for (int i = 0; i < 4; ++i) {
        int gm = m0 + ty * 4 + i;
        if (gm >= M) continue;
        #pragma unroll
        for (int j = 0; j < 4; ++j) {
            int gn = n0 + tx * 4 + j;
            float v = acc[i][j];
            if (bias) v += bias[gn];
            C[(size_t)gm * N + gn] = v;
        }
    }
}

// ---------------------------------------------------------------------------
// Kernel 3: fused flash attention, split-bf16 MFMA.
// Block = (i0: 64 rows, b, h); grid 8x8x8 = 512 blocks = exactly 2/CU.
// 4 waves; wave w owns i-rows [i0+16w, i0+16w+16): private online softmax.
// Energy: e = (qu.k + qv.P[i-j+511]) * scale  (biases folded into qu/qv),
//   diag -> -FLT_MAX, * exp(tau).
// BD term: QP = qv @ P_band^T via MFMA, gathered through per-wave LDS tile.
// All fp32 values split hi/lo bf16; products hi*hi + hi*lo + lo*hi.
// MFMA frag convention (verified m92/m97 gemm_bt): A and B^T both loaded as
// rows [idx = lane&15][k = quad*8 + t]; C/D: col = lane&15, row = quad*4+reg.
// LDS = 74.25 KB -> 2 blocks/CU.
// ---------------------------------------------------------------------------
#define PSTR 72    // bf16 row stride (144 B, 16B-aligned, conflict-free)

struct WU {        // per-wave scratch: QP gather tile, then p hi/lo (aliased;
    union {        // qp reads complete before p writes in program order)
        float    qp[16][81];
        ushort_t p[2][16][PSTR];
    };
};

__global__ __launch_bounds__(256, 2) void attn_kernel(
        const float* __restrict__ qkv, const float* __restrict__ table,
        const float* __restrict__ pos_u, const float* __restrict__ pos_v,
        const float* __restrict__ tau, float* __restrict__ outp) {
    const int i0 = blockIdx.x * 64;
    const int b  = blockIdx.y;
    const int h  = blockIdx.z;
    const int tid  = threadIdx.x;
    const int lane = tid & 63;
    const int w    = tid >> 6;
    const int c    = lane & 15;
    const int quad = lane >> 4;

    __shared__ __align__(16) ushort_t K_hi[64][PSTR], K_lo[64][PSTR];   // K, then V^T
    __shared__ __align__(16) ushort_t P_hi[128][PSTR], P_lo[128][PSTR];
    __shared__ __align__(16) WU wbuf[4];

    const float tauexp = expf(tau[0]);
    const float scale  = 0.125f;             // 64^-0.5
    const float NEGMAX = -3.4028234663852886e38f;

    // ---- build persistent q fragments (qu = q+u, qv = q+v), hi/lo ----
    frag16 qu_h[2], qu_l[2], qv_h[2], qv_l[2];
    {
        int row = i0 + w * 16 + c;
        const float* qp = qkv + ((size_t)row * BB + b) * (3 * DD) + h * DHH;
        const float* up = pos_u + h * DHH;
        const float* vp = pos_v + h * DHH;
        #pragma unroll
        for (int kb = 0; kb < 2; ++kb) {
            int d0 = kb * 32 + quad * 8;
            union { frag16 v; ushort_t s[8]; } UH, UL, VH, VL;
            #pragma unroll
            for (int t = 0; t < 8; ++t) {
                float q = qp[d0 + t];
                float a = q + up[d0 + t];
                ushort_t ah = f2bf(a);
                UH.s[t] = ah; UL.s[t] = f2bf(a - bf2f(ah));
                float bq = q + vp[d0 + t];
                ushort_t bh = f2bf(bq);
                VH.s[t] = bh; VL.s[t] = f2bf(bq - bf2f(bh));
            }
            qu_h[kb] = UH.v; qu_l[kb] = UL.v;
            qv_h[kb] = VH.v; qv_l[kb] = VL.v;
        }
    }

    float m_r[4], l_r[4];
    f32x4 o_acc[4];
    #pragma unroll
    for (int r = 0; r < 4; ++r) { m_r[r] = NEGMAX; l_r[r] = 0.f; }
    #pragma unroll
    for (int d = 0; d < 4; ++d) o_acc[d] = (f32x4){0.f, 0.f, 0.f, 0.f};

    for (int jt = 0; jt < 8; ++jt) {
        const int j0  = jt * 64;
        const int rlo = i0 - j0 + 448;       // block band origin in table rows

        __syncthreads();                     // prev-iter readers done

        // stage K tile (64 j x 64 d): thread: j = tid>>2, 16 d's
        {
            int j = tid >> 2, d0 = (tid & 3) * 16;
            const float* src = qkv + ((size_t)(j0 + j) * BB + b) * (3 * DD) + DD + h * DHH + d0;
            float x[16];
            *(float4*)&x[0]  = *(const float4*)(src + 0);
            *(float4*)&x[4]  = *(const float4*)(src + 4);
            *(float4*)&x[8]  = *(const float4*)(src + 8);
            *(float4*)&x[12] = *(const float4*)(src + 12);
            split_store8(&x[0], &K_hi[j][d0],     &K_lo[j][d0]);
            split_store8(&x[8], &K_hi[j][d0 + 8], &K_lo[j][d0 + 8]);
        }
        // stage P band (128 rows x 64 d): thread: r = tid>>1, 32 d's
        {
            int r = tid >> 1, d0 = (tid & 1) * 32;
            int rg = rlo + r; if (rg > 1022) rg = 1022;   // row 127 unused band edge
            const float* src = table + (size_t)rg * DD + h * DHH + d0;
            float x[32];
            #pragma unroll
            for (int g = 0; g < 8; ++g)
                *(float4*)&x[g * 4] = *(const float4*)(src + g * 4);
            #pragma unroll
            for (int g = 0; g < 4; ++g)
                split_store8(&x[g * 8], &P_hi[r][d0 + g * 8], &P_lo[r][d0 + g * 8]);
        }
        __syncthreads();

        // ---- QP = qv @ P_band^T (16 x 80), write to per-wave LDS ----
        f32x4 qp_acc[5];
        #pragma unroll
        for (int rs = 0; rs < 5; ++rs) {
            f32x4 acc = (f32x4){0.f, 0.f, 0.f, 0.f};
            int prow = w * 16 + rs * 16 + c;
            #pragma unroll
            for (int kb = 0; kb < 2; ++kb) {
                frag16 ph = *(const frag16*)&P_hi[prow][kb * 32 + quad * 8];
                frag16 pl = *(const frag16*)&P_lo[prow][kb * 32 + quad * 8];
                acc = MFMA16(qv_h[kb], ph, acc, 0, 0, 0);
                acc = MFMA16(qv_h[kb], pl, acc, 0, 0, 0);
                acc = MFMA16(qv_l[kb], ph, acc, 0, 0, 0);
            }
            qp_acc[rs] = acc;
        }
        #pragma unroll
        for (int rs = 0; rs < 5; ++rs)
            #pragma unroll
            for (int reg = 0; reg < 4; ++reg)
                wbuf[w].qp[quad * 4 + reg][rs * 16 + c] = qp_acc[rs][reg];

        // ---- AC = qu @ K^T (16 x 64) ----
        f32x4 ac[4];
        #pragma unroll
        for (int js = 0; js < 4; ++js) {
            f32x4 acc = (f32x4){0.f, 0.f, 0.f, 0.f};
            int krow = js * 16 + c;
            #pragma unroll
            for (int kb = 0; kb < 2; ++kb) {
                frag16 kh = *(const frag16*)&K_hi[krow][kb * 32 + quad * 8];
                frag16 kl = *(const frag16*)&K_lo[krow][kb * 32 + quad * 8];
                acc = MFMA16(qu_h[kb], kh, acc, 0, 0, 0);
                acc = MFMA16(qu_h[kb], kl, acc, 0, 0, 0);
                acc = MFMA16(qu_l[kb], kh, acc, 0, 0, 0);
            }
            ac[js] = acc;
        }

        // ---- energy assembly: gather BD, mask, temperature ----
        float ev[4][4];
        #pragma unroll
        for (int js = 0; js < 4; ++js) {
            int jl = js * 16 + c;
            #pragma unroll
            for (int reg = 0; reg < 4; ++reg) {
                int il = quad * 4 + reg;
                float bd = wbuf[w].qp[il][il - jl + 63];
                float e = (ac[js][reg] + bd) * scale;
                if (i0 + w * 16 + il == j0 + jl) e = NEGMAX;
                ev[js][reg] = e * tauexp;
            }
        }

        // ---- online softmax (rows private to quad; reduce over 16 lanes) ----
        float alpha[4], mn[4];
        #pragma unroll
        for (int reg = 0; reg < 4; ++reg) {
            float mx = fmaxf(fmaxf(ev[0][reg], ev[1][reg]),
                             fmaxf(ev[2][reg], ev[3][reg]));
            #pragma unroll
            for (int m = 1; m < 16; m <<= 1) mx = fmaxf(mx, __shfl_xor(mx, m));
            float m2 = fmaxf(m_r[reg], mx);
            alpha[reg] = __expf(m_r[reg] - m2);
            mn[reg] = m2;
            m_r[reg] = m2;
        }
        float ss[4] = {0.f, 0.f, 0.f, 0.f};
        #pragma unroll
        for (int js = 0; js < 4; ++js) {
            int jl = js * 16 + c;
            #pragma unroll
            for (int reg = 0; reg < 4; ++reg) {
                float p = __expf(ev[js][reg] - mn[reg]);
                ss[reg] += p;
                ushort_t ph = f2bf(p);
                wbuf[w].p[0][quad * 4 + reg][jl] = ph;
                wbuf[w].p[1][quad * 4 + reg][jl] = f2bf(p - bf2f(ph));
            }
        }
        #pragma unroll
        for (int reg = 0; reg < 4; ++reg) {
            float s = ss[reg];
            #pragma unroll
            for (int m = 1; m < 16; m <<= 1) s += __shfl_xor(s, m);
            l_r[reg] = l_r[reg] * alpha[reg] + s;
        }

        __syncthreads();                     // all waves done with K_s
        // stage V^T (d-major) into K buffer: thread: j = tid&63, 16 d's
        {
            int j = tid & 63, dg = tid >> 6;
            const float* src = qkv + ((size_t)(j0 + j) * BB + b) * (3 * DD) + 2 * DD + h * DHH + dg * 16;
            float x[16];
            *(float4*)&x[0]  = *(const float4*)(src + 0);
            *(float4*)&x[4]  = *(const float4*)(src + 4);
            *(float4*)&x[8]  = *(const float4*)(src + 8);
            *(float4*)&x[12] = *(const float4*)(src + 12);
            #pragma unroll
            for (int t = 0; t < 16; ++t) {
                int d = dg * 16 + t;
                ushort_t hh = f2bf(x[t]);
                K_hi[d][j] = hh;
                K_lo[d][j] = f2bf(x[t] - bf2f(hh));
            }
        }
        __syncthreads();

        // ---- O = O*alpha + p @ V ----
        frag16 pfh[2], pfl[2];
        #pragma unroll
        for (int kb = 0; kb < 2; ++kb) {
            pfh[kb] = *(const frag16*)&wbuf[w].p[0][c][kb * 32 + quad * 8];
            pfl[kb] = *(const frag16*)&wbuf[w].p[1][c][kb * 32 + quad * 8];
        }
        #pragma unroll
        for (int ds = 0; ds < 4; ++ds) {
            f32x4 acc = o_acc[ds];
            #pragma unroll
            for (int reg = 0; reg < 4; ++reg) acc[reg] *= alpha[reg];
            #pragma unroll
            for (int kb = 0; kb < 2; ++kb) {
                frag16 vh = *(const frag16*)&K_hi[ds * 16 + c][kb * 32 + quad * 8];
                frag16 vl = *(const frag16*)&K_lo[ds * 16 + c][kb * 32 + quad * 8];
                acc = MFMA16(pfh[kb], vh, acc, 0, 0, 0);
                acc = MFMA16(pfh[kb], vl, acc, 0, 0, 0);
                acc = MFMA16(pfl[kb], vh, acc, 0, 0, 0);
            }
            o_acc[ds] = acc;
        }
    }

    // ---- epilogue: normalize and store ----
    #pragma unroll
    for (int ds = 0; ds < 4; ++ds)
        #pragma unroll
        for (int reg = 0; reg < 4; ++reg) {
            int row = i0 + w * 16 + quad * 4 + reg;
            outp[((size_t)row * BB + b) * DD + h * DHH + ds * 16 + c] =
                o_acc[ds][reg] / l_r[reg];
        }
}

// ---------------------------------------------------------------------------
// launch
// ---------------------------------------------------------------------------
extern "C" void kernel_launch(void* const* d_in, const int* in_sizes, int n_in,
                              void* d_out, int out_size, void* d_ws, size_t ws_size,
                              hipStream_t stream) {
    const float* x     = (const float*)d_in[0];   // (512, 8, 512)
    const float* W_qkv = (const float*)d_in[1];   // (512, 1536)
    const float* W_pos = (const float*)d_in[2];   // (512, 512)
    const float* pos_u = (const float*)d_in[3];   // (8, 64)
    const float* pos_v = (const float*)d_in[4];   // (8, 64)
    const float* W_out = (const float*)d_in[5];   // (512, 512)
    const float* b_out = (const float*)d_in[6];   // (512,)
    const float* tau   = (const float*)d_in[7];   // (1,)
    float* out = (float*)d_out;                   // (512, 8, 512)

    float* ws    = (float*)d_ws;
    float* feat  = ws;                            // 1023*512
    float* table = feat + (size_t)NR * DD;        // 1023*512
    float* qkvb  = table + (size_t)NR * DD;       // 4096*1536
    float* attno = qkvb + (size_t)(TT * BB) * (3 * DD);  // 4096*512

    // 1. sinusoid features
    feat_kernel<<<(NR * DD + 255) / 256, 256, 0, stream>>>(feat);
    // 2. table = feat @ W_pos   (1023 x 512 x 512)
    gemm_kernel<<<dim3(DD / BN, (NR + BM - 1) / BM), 256, 0, stream>>>(
        feat, W_pos, nullptr, table, NR, DD, DD);
    // 3. qkv = x @ W_qkv   (4096 x 1536 x 512)
    gemm_kernel<<<dim3((3 * DD) / BN, (TT * BB) / BM), 256, 0, stream>>>(
        x, W_qkv, nullptr, qkvb, TT * BB, 3 * DD, DD);
    // 4. fused flash attention (MFMA) -> attno
    attn_kernel<<<dim3(TT / 64, BB, HH), 256, 0, stream>>>(
        qkvb, table, pos_u, pos_v, tau, attno);
    // 5. out = attno @ W_out + b_out   (4096 x 512 x 512)
    gemm_kernel<<<dim3(DD / BN, (TT * BB) / BM), 256, 0, stream>>>(
        attno, W_out, b_out, out, TT * BB, DD, DD);
}

// Round 4
// 214.475 us; speedup vs baseline: 4.1868x; 1.5907x over previous
//
#include <hip/hip_runtime.h>
#include <hip/hip_bf16.h>

// Problem constants: T=512, B=8, D=512, H=8, DH=64
#define TT 512
#define BB 8
#define DD 512
#define HH 8
#define DHH 64

typedef unsigned short ushort_t;
using frag16 = __attribute__((ext_vector_type(8))) short;     // 8 bf16
using f32x4  = __attribute__((ext_vector_type(4))) float;     // MFMA acc
using usx4   = __attribute__((ext_vector_type(4))) ushort_t;  // 4 bf16

#define MFMA16 __builtin_amdgcn_mfma_f32_16x16x32_bf16

__device__ inline ushort_t f2bf(float x) {
    __hip_bfloat16 h = __float2bfloat16(x);
    ushort_t u; __builtin_memcpy(&u, &h, 2); return u;
}
__device__ inline float bf2f(ushort_t u) {
    __hip_bfloat16 h; __builtin_memcpy(&h, &u, 2);
    return __bfloat162float(h);
}

// async global->LDS, 16 B per lane; lds dest must be wave-uniform
__device__ inline void gload16(const void* g, void* l) {
    __builtin_amdgcn_global_load_lds(
        (const __attribute__((address_space(1))) unsigned int*)g,
        (__attribute__((address_space(3))) unsigned int*)l, 16, 0, 0);
}

// ---------------------------------------------------------------------------
// Kernel 1: sinusoid feature table -> hi/lo bf16 planes [1024][512]
// (row 1023 is padding; finite values, never consumed downstream)
// ---------------------------------------------------------------------------
__global__ __launch_bounds__(256) void feat_kernel(
        ushort_t* __restrict__ fh, ushort_t* __restrict__ fl) {
    int idx = blockIdx.x * 256 + threadIdx.x;      // 1024*512 total
    int r = idx >> 9;
    int c = idx & 511;
    float dist = (float)(r - 511);
    int cc = c & 255;
    float freq = expf((-logf(10000.0f) * (float)cc) / 256.0f);
    float ang = dist * freq;
    float v = (c < 256) ? sinf(ang) : cosf(ang);
    ushort_t hh = f2bf(v);
    fh[idx] = hh;
    fl[idx] = f2bf(v - bf2f(hh));
}

// ---------------------------------------------------------------------------
// Kernel 2: elementwise fp32 -> hi/lo bf16 planes (same layout). For x.
// ---------------------------------------------------------------------------
__global__ __launch_bounds__(256) void split_rows(
        const float* __restrict__ in, ushort_t* __restrict__ oh,
        ushort_t* __restrict__ ol) {
    int i = blockIdx.x * 256 + threadIdx.x;        // handles 4 elems
    float4 v = ((const float4*)in)[i];
    float x[4] = {v.x, v.y, v.z, v.w};
    usx4 H, L;
    #pragma unroll
    for (int t = 0; t < 4; ++t) {
        ushort_t hh = f2bf(x[t]);
        H[t] = hh;
        L[t] = f2bf(x[t] - bf2f(hh));
    }
    ((usx4*)oh)[i] = H;
    ((usx4*)ol)[i] = L;
}

// ---------------------------------------------------------------------------
// Kernel 3: transpose+split: in fp32 [K][N] -> hi/lo bf16 planes [N][K].
// 32x32 LDS tile.
// ---------------------------------------------------------------------------
__global__ __launch_bounds__(256) void split_t(
        const float* __restrict__ in, ushort_t* __restrict__ oh,
        ushort_t* __restrict__ ol, int K, int N) {
    __shared__ float tile[32][33];
    int n0 = blockIdx.x * 32, k0 = blockIdx.y * 32;
    int tid = threadIdx.x;
    {
        int r = tid >> 3, c0 = (tid & 7) * 4;
        float4 v = *(const float4*)&in[(size_t)(k0 + r) * N + n0 + c0];
        tile[r][c0] = v.x; tile[r][c0 + 1] = v.y;
        tile[r][c0 + 2] = v.z; tile[r][c0 + 3] = v.w;
    }
    __syncthreads();
    {
        int n = tid >> 3, kk = (tid & 7) * 4;
        usx4 H, L;
        #pragma unroll
        for (int t = 0; t < 4; ++t) {
            float x = tile[kk + t][n];
            ushort_t hh = f2bf(x);
            H[t] = hh;
            L[t] = f2bf(x - bf2f(hh));
        }
        *(usx4*)&oh[(size_t)(n0 + n) * K + k0 + kk] = H;
        *(usx4*)&ol[(size_t)(n0 + n) * K + k0 + kk] = L;
    }
}

// ---------------------------------------------------------------------------
// Kernel 4: split-bf16 MFMA GEMM.  C[M][N] = A[M][K] @ BT[N][K]^T
// A, B given as hi/lo bf16 planes. 3 products: hh + hl + lh (~fp32 accuracy).
// Tile TM x TN, BK=32, 256 threads = 4 waves (2x2), wave covers TM/2 x TN/2.
// LDS layout: 16B cells, index (region, plane, quad, row) -> ds_read_b128
// fragment reads are stride-16B across lanes (<=2-way bank alias, free).
// Staged via global_load_lds (1 KB chunk per issue, 64 lanes x 16 B).
// MODE 0: write fp32 C + bias.  MODE 1: write hi/lo bf16 planes.
// ---------------------------------------------------------------------------
template <int TM, int TN, int MODE>
__global__ __launch_bounds__(256) void gemm_bf3(
        const ushort_t* __restrict__ Ah, const ushort_t* __restrict__ Al,
        const ushort_t* __restrict__ Bh, const ushort_t* __restrict__ Bl,
        const float* __restrict__ bias, float* __restrict__ C,
        ushort_t* __restrict__ Ch, ushort_t* __restrict__ Cl,
        int M, int N, int K) {
    constexpr int NMI = TM / 32;          // 16x16 m-tiles per wave
    constexpr int NNI = TN / 32;
    constexpr int ACH = TM / 8;           // 1 KB staging chunks for A region
    constexpr int BCH = TN / 8;
    constexpr int NCH = ACH + BCH;

    __shared__ ushort_t lds[64 * (TM + TN)];   // 128*(TM+TN) bytes

    const int tid = threadIdx.x;
    const int lane = tid & 63;
    const int w = tid >> 6;
    const int wm = w & 1, wn = w >> 1;
    const int c = lane & 15, quad = lane >> 4;
    const int m0 = blockIdx.y * TM;
    const int n0 = blockIdx.x * TN;

    f32x4 acc[NMI][NNI];
    #pragma unroll
    for (int mi = 0; mi < NMI; ++mi)
        #pragma unroll
        for (int ni = 0; ni < NNI; ++ni)
            acc[mi][ni] = (f32x4){0.f, 0.f, 0.f, 0.f};

    for (int k0 = 0; k0 < K; k0 += 32) {
        __syncthreads();                       // prev-iter frag reads done
        #pragma unroll
        for (int ci = 0; ci < NCH / 4; ++ci) {
            int ch = ci * 4 + w;               // wave-uniform chunk id
            const ushort_t* src;
            int cell;
            if (ch < ACH) {
                int plane = ch / (TM / 16);
                int rem   = ch % (TM / 16);
                int q     = rem / (TM / 64);
                int r0    = (rem % (TM / 64)) * 64;
                src  = (plane ? Al : Ah) + (size_t)(m0 + r0 + lane) * K + k0 + q * 8;
                cell = (plane * 4 + q) * TM + r0;
            } else {
                int bh    = ch - ACH;
                int plane = bh / (TN / 16);
                int rem   = bh % (TN / 16);
                int q     = rem / (TN / 64);
                int r0    = (rem % (TN / 64)) * 64;
                src  = (plane ? Bl : Bh) + (size_t)(n0 + r0 + lane) * K + k0 + q * 8;
                cell = 8 * TM + (plane * 4 + q) * TN + r0;
            }
            gload16(src, &lds[(size_t)cell * 8]);
        }
        __syncthreads();                       // vmcnt(0) drained by barrier

        frag16 a_h[NMI], a_l[NMI], b_h[NNI], b_l[NNI];
        #pragma unroll
        for (int mi = 0; mi < NMI; ++mi) {
            int arow = wm * (TM / 2) + mi * 16 + c;
            a_h[mi] = *(const frag16*)&lds[((0 * 4 + quad) * TM + arow) * 8];
            a_l[mi] = *(const frag16*)&lds[((1 * 4 + quad) * TM + arow) * 8];
        }
        #pragma unroll
        for (int ni = 0; ni < NNI; ++ni) {
            int brow = wn * (TN / 2) + ni * 16 + c;
            b_h[ni] = *(const frag16*)&lds[(8 * TM + (0 * 4 + quad) * TN + brow) * 8];
            b_l[ni] = *(const frag16*)&lds[(8 * TM + (1 * 4 + quad) * TN + brow) * 8];
        }
        #pragma unroll
        for (int mi = 0; mi < NMI; ++mi)
            #pragma unroll
            for (int ni = 0; ni < NNI; ++ni) {
                acc[mi][ni] = MFMA16(a_h[mi], b_h[ni], acc[mi][ni], 0, 0, 0);
                acc[mi][ni] = MFMA16(a_h[mi], b_l[ni], acc[mi][ni], 0, 0, 0);
                acc[mi][ni] = MFMA16(a_l[mi], b_h[ni], acc[mi][ni], 0, 0, 0);
            }
    }

    // epilogue: D row = quad*4+reg (m), col = c (n)
    #pragma unroll
    for (int mi = 0; mi < NMI; ++mi)
        #pragma unroll
        for (int ni = 0; ni < NNI; ++ni)
            #pragma unroll
            for (int reg = 0; reg < 4; ++reg) {
                int gm = m0 + wm * (TM / 2) + mi * 16 + quad * 4 + reg;
                int gn = n0 + wn * (TN / 2) + ni * 16 + c;
                float v = acc[mi][ni][reg];
                if (MODE == 0) {
                    C[(size_t)gm * N + gn] = v + bias[gn];
                } else {
                    ushort_t hh = f2bf(v);
                    Ch[(size_t)gm * N + gn] = hh;
                    Cl[(size_t)gm * N + gn] = f2bf(v - bf2f(hh));
                }
            }
}

// ---------------------------------------------------------------------------
// Kernel 5: fused flash attention, split-bf16 MFMA (structure verified R3).
// Inputs now pre-split hi/lo planes -> staging is pure vector copies.
// Output: hi/lo bf16 planes of attno (A of the out-projection GEMM).
// ---------------------------------------------------------------------------
#define PSTR 72    // bf16 LDS row stride (144 B, odd-quad -> conflict-free)

struct WU {
    union {
        float    qp[16][81];
        ushort_t p[2][16][PSTR];
    };
};

__global__ __launch_bounds__(256, 2) void attn_kernel(
        const ushort_t* __restrict__ qkv_h, const ushort_t* __restrict__ qkv_l,
        const ushort_t* __restrict__ T_h, const ushort_t* __restrict__ T_l,
        const float* __restrict__ pos_u, const float* __restrict__ pos_v,
        const float* __restrict__ tau,
        ushort_t* __restrict__ o_h, ushort_t* __restrict__ o_l) {
    const int i0 = blockIdx.x * 64;
    const int b  = blockIdx.y;
    const int h  = blockIdx.z;
    const int tid  = threadIdx.x;
    const int lane = tid & 63;
    const int w    = tid >> 6;
    const int c    = lane & 15;
    const int quad = lane >> 4;

    __shared__ __align__(16) ushort_t K_hi[64][PSTR], K_lo[64][PSTR];
    __shared__ __align__(16) ushort_t P_hi[128][PSTR], P_lo[128][PSTR];
    __shared__ __align__(16) WU wbuf[4];

    const float tauexp = expf(tau[0]);
    const float scale  = 0.125f;
    const float NEGMAX = -3.4028234663852886e38f;

    // ---- persistent q fragments (qu = q+u, qv = q+v), hi/lo split ----
    frag16 qu_h[2], qu_l[2], qv_h[2], qv_l[2];
    {
        int row = i0 + w * 16 + c;
        size_t base = ((size_t)row * BB + b) * (3 * DD) + h * DHH;
        const float* up = pos_u + h * DHH;
        const float* vp = pos_v + h * DHH;
        #pragma unroll
        for (int kb = 0; kb < 2; ++kb) {
            int d0 = kb * 32 + quad * 8;
            union { frag16 v; ushort_t s[8]; } QH, QL, UH, UL, VH, VL;
            QH.v = *(const frag16*)&qkv_h[base + d0];
            QL.v = *(const frag16*)&qkv_l[base + d0];
            #pragma unroll
            for (int t = 0; t < 8; ++t) {
                float q = bf2f(QH.s[t]) + bf2f(QL.s[t]);
                float a = q + up[d0 + t];
                ushort_t ah = f2bf(a);
                UH.s[t] = ah; UL.s[t] = f2bf(a - bf2f(ah));
                float bq = q + vp[d0 + t];
                ushort_t bh = f2bf(bq);
                VH.s[t] = bh; VL.s[t] = f2bf(bq - bf2f(bh));
            }
            qu_h[kb] = UH.v; qu_l[kb] = UL.v;
            qv_h[kb] = VH.v; qv_l[kb] = VL.v;
        }
    }

    float m_r[4], l_r[4];
    f32x4 o_acc[4];
    #pragma unroll
    for (int r = 0; r < 4; ++r) { m_r[r] = NEGMAX; l_r[r] = 0.f; }
    #pragma unroll
    for (int d = 0; d < 4; ++d) o_acc[d] = (f32x4){0.f, 0.f, 0.f, 0.f};

    for (int jt = 0; jt < 8; ++jt) {
        const int j0  = jt * 64;
        const int rlo = i0 - j0 + 448;

        __syncthreads();

        // stage K tile (64 x 64): thread: row = tid>>2, 16 d's, both planes
        {
            int j = tid >> 2, d0 = (tid & 3) * 16;
            size_t kb2 = ((size_t)(j0 + j) * BB + b) * (3 * DD) + DD + h * DHH + d0;
            *(frag16*)&K_hi[j][d0]     = *(const frag16*)&qkv_h[kb2];
            *(frag16*)&K_hi[j][d0 + 8] = *(const frag16*)&qkv_h[kb2 + 8];
            *(frag16*)&K_lo[j][d0]     = *(const frag16*)&qkv_l[kb2];
            *(frag16*)&K_lo[j][d0 + 8] = *(const frag16*)&qkv_l[kb2 + 8];
        }
        // stage P band (128 x 64): thread: row = tid>>1, 32 d's, both planes
        {
            int r = tid >> 1, d0 = (tid & 1) * 32;
            size_t tb = (size_t)(rlo + r) * DD + h * DHH + d0;
            #pragma unroll
            for (int g = 0; g < 4; ++g) {
                *(frag16*)&P_hi[r][d0 + g * 8] = *(const frag16*)&T_h[tb + g * 8];
                *(frag16*)&P_lo[r][d0 + g * 8] = *(const frag16*)&T_l[tb + g * 8];
            }
        }
        __syncthreads();

        // ---- QP = qv @ P_band^T (16 x 80) -> per-wave LDS ----
        f32x4 qp_acc[5];
        #pragma unroll
        for (int rs = 0; rs < 5; ++rs) {
            f32x4 acc = (f32x4){0.f, 0.f, 0.f, 0.f};
            int prow = w * 16 + rs * 16 + c;
            #pragma unroll
            for (int kb = 0; kb < 2; ++kb) {
                frag16 ph = *(const frag16*)&P_hi[prow][kb * 32 + quad * 8];
                frag16 pl = *(const frag16*)&P_lo[prow][kb * 32 + quad * 8];
                acc = MFMA16(qv_h[kb], ph, acc, 0, 0, 0);
                acc = MFMA16(qv_h[kb], pl, acc, 0, 0, 0);
                acc = MFMA16(qv_l[kb], ph, acc, 0, 0, 0);
            }
            qp_acc[rs] = acc;
        }
        #pragma unroll
        for (int rs = 0; rs < 5; ++rs)
            #pragma unroll
            for (int reg = 0; reg < 4; ++reg)
                wbuf[w].qp[quad * 4 + reg][rs * 16 + c] = qp_acc[rs][reg];

        // ---- AC = qu @ K^T (16 x 64) ----
        f32x4 ac[4];
        #pragma unroll
        for (int js = 0; js < 4; ++js) {
            f32x4 acc = (f32x4){0.f, 0.f, 0.f, 0.f};
            int krow = js * 16 + c;
            #pragma unroll
            for (int kb = 0; kb < 2; ++kb) {
                frag16 kh = *(const frag16*)&K_hi[krow][kb * 32 + quad * 8];
                frag16 kl = *(const frag16*)&K_lo[krow][kb * 32 + quad * 8];
                acc = MFMA16(qu_h[kb], kh, acc, 0, 0, 0);
                acc = MFMA16(qu_h[kb], kl, acc, 0, 0, 0);
                acc = MFMA16(qu_l[kb], kh, acc, 0, 0, 0);
            }
            ac[js] = acc;
        }

        // ---- energy assembly ----
        float ev[4][4];
        #pragma unroll
        for (int js = 0; js < 4; ++js) {
            int jl = js * 16 + c;
            #pragma unroll
            for (int reg = 0; reg < 4; ++reg) {
                int il = quad * 4 + reg;
                float bd = wbuf[w].qp[il][il - jl + 63];
                float e = (ac[js][reg] + bd) * scale;
                if (i0 + w * 16 + il == j0 + jl) e = NEGMAX;
                ev[js][reg] = e * tauexp;
            }
        }

        // ---- online softmax (quad-private rows, 16-lane reduce) ----
        float alpha[4], mn[4];
        #pragma unroll
        for (int reg = 0; reg < 4; ++reg) {
            float mx = fmaxf(fmaxf(ev[0][reg], ev[1][reg]),
                             fmaxf(ev[2][reg], ev[3][reg]));
            #pragma unroll
            for (int m = 1; m < 16; m <<= 1) mx = fmaxf(mx, __shfl_xor(mx, m));
            float m2 = fmaxf(m_r[reg], mx);
            alpha[reg] = __expf(m_r[reg] - m2);
            mn[reg] = m2;
            m_r[reg] = m2;
        }
        float ss[4] = {0.f, 0.f, 0.f, 0.f};
        #pragma unroll
        for (int js = 0; js < 4; ++js) {
            int jl = js * 16 + c;
            #pragma unroll
            for (int reg = 0; reg < 4; ++reg) {
                float p = __expf(ev[js][reg] - mn[reg]);
                ss[reg] += p;
                ushort_t ph = f2bf(p);
                wbuf[w].p[0][quad * 4 + reg][jl] = ph;
                wbuf[w].p[1][quad * 4 + reg][jl] = f2bf(p - bf2f(ph));
            }
        }
        #pragma unroll
        for (int reg = 0; reg < 4; ++reg) {
            float s = ss[reg];
            #pragma unroll
            for (int m = 1; m < 16; m <<= 1) s += __shfl_xor(s, m);
            l_r[reg] = l_r[reg] * alpha[reg] + s;
        }

        __syncthreads();
        // stage V^T (d-major) into K buffer from planes
        {
            int j = tid & 63, dg = tid >> 6;
            size_t vb = ((size_t)(j0 + j) * BB + b) * (3 * DD) + 2 * DD + h * DHH + dg * 16;
            union { frag16 v; ushort_t s[8]; } H0, H1, L0, L1;
            H0.v = *(const frag16*)&qkv_h[vb];
            H1.v = *(const frag16*)&qkv_h[vb + 8];
            L0.v = *(const frag16*)&qkv_l[vb];
            L1.v = *(const frag16*)&qkv_l[vb + 8];
            #pragma unroll
            for (int t = 0; t < 8; ++t) {
                K_hi[dg * 16 + t][j]     = H0.s[t];
                K_hi[dg * 16 + 8 + t][j] = H1.s[t];
                K_lo[dg * 16 + t][j]     = L0.s[t];
                K_lo[dg * 16 + 8 + t][j] = L1.s[t];
            }
        }
        __syncthreads();

        // ---- O = O*alpha + p @ V ----
        frag16 pfh[2], pfl[2];
        #pragma unroll
        for (int kb = 0; kb < 2; ++kb) {
            pfh[kb] = *(const frag16*)&wbuf[w].p[0][c][kb * 32 + quad * 8];
            pfl[kb] = *(const frag16*)&wbuf[w].p[1][c][kb * 32 + quad * 8];
        }
        #pragma unroll
        for (int ds = 0; ds < 4; ++ds) {
            f32x4 acc = o_acc[ds];
            #pragma unroll
            for (int reg = 0; reg < 4; ++reg) acc[reg] *= alpha[reg];
            #pragma unroll
            for (int kb = 0; kb < 2; ++kb) {
                frag16 vh = *(const frag16*)&K_hi[ds * 16 + c][kb * 32 + quad * 8];
                frag16 vl = *(const frag16*)&K_lo[ds * 16 + c][kb * 32 + quad * 8];
                acc = MFMA16(pfh[kb], vh, acc, 0, 0, 0);
                acc = MFMA16(pfh[kb], vl, acc, 0, 0, 0);
                acc = MFMA16(pfl[kb], vh, acc, 0, 0, 0);
            }
            o_acc[ds] = acc;
        }
    }

    // ---- epilogue: normalize, split, store planes ----
    #pragma unroll
    for (int ds = 0; ds < 4; ++ds)
        #pragma unroll
        for (int reg = 0; reg < 4; ++reg) {
            int row = i0 + w * 16 + quad * 4 + reg;
            size_t idx = ((size_t)row * BB + b) * DD + h * DHH + ds * 16 + c;
            float val = o_acc[ds][reg] / l_r[reg];
            ushort_t hh = f2bf(val);
            o_h[idx] = hh;
            o_l[idx] = f2bf(val - bf2f(hh));
        }
}

// ---------------------------------------------------------------------------
// launch
// ---------------------------------------------------------------------------
extern "C" void kernel_launch(void* const* d_in, const int* in_sizes, int n_in,
                              void* d_out, int out_size, void* d_ws, size_t ws_size,
                              hipStream_t stream) {
    const float* x     = (const float*)d_in[0];   // (512, 8, 512)
    const float* W_qkv = (const float*)d_in[1];   // (512, 1536)
    const float* W_pos = (const float*)d_in[2];   // (512, 512)
    const float* pos_u = (const float*)d_in[3];   // (8, 64)
    const float* pos_v = (const float*)d_in[4];   // (8, 64)
    const float* W_out = (const float*)d_in[5];   // (512, 512)
    const float* b_out = (const float*)d_in[6];   // (512,)
    const float* tau   = (const float*)d_in[7];   // (1,)
    float* out = (float*)d_out;                   // (512, 8, 512)

    ushort_t* p = (ushort_t*)d_ws;
    ushort_t* feat_h  = p; p += 1024 * 512;
    ushort_t* feat_l  = p; p += 1024 * 512;
    ushort_t* WposT_h = p; p += 512 * 512;
    ushort_t* WposT_l = p; p += 512 * 512;
    ushort_t* table_h = p; p += 1024 * 512;
    ushort_t* table_l = p; p += 1024 * 512;
    ushort_t* x_h     = p; p += 4096 * 512;
    ushort_t* x_l     = p; p += 4096 * 512;
    ushort_t* WqkvT_h = p; p += 1536 * 512;
    ushort_t* WqkvT_l = p; p += 1536 * 512;
    ushort_t* qkv_h   = p; p += 4096 * 1536;
    ushort_t* qkv_l   = p; p += 4096 * 1536;
    ushort_t* WoutT_h = p; p += 512 * 512;
    ushort_t* WoutT_l = p; p += 512 * 512;
    ushort_t* ao_h    = p; p += 4096 * 512;
    ushort_t* ao_l    = p; p += 4096 * 512;

    // input prep
    feat_kernel<<<2048, 256, 0, stream>>>(feat_h, feat_l);
    split_rows<<<2048, 256, 0, stream>>>(x, x_h, x_l);
    split_t<<<dim3(16, 16), 256, 0, stream>>>(W_pos, WposT_h, WposT_l, 512, 512);
    split_t<<<dim3(48, 16), 256, 0, stream>>>(W_qkv, WqkvT_h, WqkvT_l, 512, 1536);
    split_t<<<dim3(16, 16), 256, 0, stream>>>(W_out, WoutT_h, WoutT_l, 512, 512);

    // table = feat @ W_pos  (1024 x 512 x 512), split output
    gemm_bf3<64, 64, 1><<<dim3(512 / 64, 1024 / 64), 256, 0, stream>>>(
        feat_h, feat_l, WposT_h, WposT_l, nullptr, nullptr, table_h, table_l,
        1024, 512, 512);
    // qkv = x @ W_qkv  (4096 x 1536 x 512), split output
    gemm_bf3<128, 128, 1><<<dim3(1536 / 128, 4096 / 128), 256, 0, stream>>>(
        x_h, x_l, WqkvT_h, WqkvT_l, nullptr, nullptr, qkv_h, qkv_l,
        4096, 1536, 512);
    // fused attention -> attno planes
    attn_kernel<<<dim3(8, 8, 8), 256, 0, stream>>>(
        qkv_h, qkv_l, table_h, table_l, pos_u, pos_v, tau, ao_h, ao_l);
    // out = attno @ W_out + b_out  (4096 x 512 x 512), fp32 output
    gemm_bf3<64, 128, 0><<<dim3(512 / 128, 4096 / 64), 256, 0, stream>>>(
        ao_h, ao_l, WoutT_h, WoutT_l, b_out, out, nullptr, nullptr,
        4096, 512, 512);
}

// Round 5
// 203.084 us; speedup vs baseline: 4.4216x; 1.0561x over previous
//
#include <hip/hip_runtime.h>
#include <hip/hip_bf16.h>

// Problem constants: T=512, B=8, D=512, H=8, DH=64
#define TT 512
#define BB 8
#define DD 512
#define HH 8
#define DHH 64

typedef unsigned short ushort_t;
using frag16 = __attribute__((ext_vector_type(8))) short;     // 8 bf16
using f32x4  = __attribute__((ext_vector_type(4))) float;     // MFMA acc
using usx4   = __attribute__((ext_vector_type(4))) ushort_t;  // 4 bf16

#define MFMA16 __builtin_amdgcn_mfma_f32_16x16x32_bf16

__device__ inline ushort_t f2bf(float x) {
    __hip_bfloat16 h = __float2bfloat16(x);
    ushort_t u; __builtin_memcpy(&u, &h, 2); return u;
}
__device__ inline float bf2f(ushort_t u) {
    __hip_bfloat16 h; __builtin_memcpy(&h, &u, 2);
    return __bfloat162float(h);
}

// async global->LDS, 16 B per lane; lds dest wave-uniform base + lane*16
__device__ inline void gload16(const void* g, void* l) {
    __builtin_amdgcn_global_load_lds(
        (const __attribute__((address_space(1))) unsigned int*)g,
        (__attribute__((address_space(3))) unsigned int*)l, 16, 0, 0);
}

// ---------------------------------------------------------------------------
// Kernel 1: fused input prep.
//   blocks [0,2048):    feat planes [1024][512]  (sinusoid table)
//   blocks [2048,4096): split x -> planes
//   blocks [4096,4352): split_t W_pos  (512x512 -> [N][K])
//   blocks [4352,5120): split_t W_qkv  (512x1536 -> [N][K])
//   blocks [5120,5376): split_t W_out  (512x512 -> [N][K])
// ---------------------------------------------------------------------------
__device__ inline void split_t_tile(const float* __restrict__ in,
                                    ushort_t* __restrict__ oh,
                                    ushort_t* __restrict__ ol,
                                    int K, int N, int bx, int by, int tid,
                                    float (*tile)[33]) {
    int n0 = bx * 32, k0 = by * 32;
    {
        int r = tid >> 3, c0 = (tid & 7) * 4;
        float4 v = *(const float4*)&in[(size_t)(k0 + r) * N + n0 + c0];
        tile[r][c0] = v.x; tile[r][c0 + 1] = v.y;
        tile[r][c0 + 2] = v.z; tile[r][c0 + 3] = v.w;
    }
    __syncthreads();
    {
        int n = tid >> 3, kk = (tid & 7) * 4;
        usx4 H, L;
        #pragma unroll
        for (int t = 0; t < 4; ++t) {
            float x = tile[kk + t][n];
            ushort_t hh = f2bf(x);
            H[t] = hh;
            L[t] = f2bf(x - bf2f(hh));
        }
        *(usx4*)&oh[(size_t)(n0 + n) * K + k0 + kk] = H;
        *(usx4*)&ol[(size_t)(n0 + n) * K + k0 + kk] = L;
    }
}

__global__ __launch_bounds__(256) void prep_kernel(
        const float* __restrict__ x, const float* __restrict__ W_pos,
        const float* __restrict__ W_qkv, const float* __restrict__ W_out,
        ushort_t* __restrict__ fh, ushort_t* __restrict__ fl,
        ushort_t* __restrict__ xh, ushort_t* __restrict__ xl,
        ushort_t* __restrict__ WposT_h, ushort_t* __restrict__ WposT_l,
        ushort_t* __restrict__ WqkvT_h, ushort_t* __restrict__ WqkvT_l,
        ushort_t* __restrict__ WoutT_h, ushort_t* __restrict__ WoutT_l) {
    __shared__ float tile[32][33];
    int blk = blockIdx.x;
    int tid = threadIdx.x;
    if (blk < 2048) {                       // feat
        int idx = blk * 256 + tid;
        int r = idx >> 9, c = idx & 511;
        float dist = (float)(r - 511);
        int cc = c & 255;
        float freq = expf((-logf(10000.0f) * (float)cc) / 256.0f);
        float ang = dist * freq;
        float v = (c < 256) ? sinf(ang) : cosf(ang);
        ushort_t hh = f2bf(v);
        fh[idx] = hh;
        fl[idx] = f2bf(v - bf2f(hh));
    } else if (blk < 4096) {                // split x (4 elems/thread)
        int i = (blk - 2048) * 256 + tid;
        float4 v = ((const float4*)x)[i];
        float e[4] = {v.x, v.y, v.z, v.w};
        usx4 H, L;
        #pragma unroll
        for (int t = 0; t < 4; ++t) {
            ushort_t hh = f2bf(e[t]);
            H[t] = hh;
            L[t] = f2bf(e[t] - bf2f(hh));
        }
        ((usx4*)xh)[i] = H;
        ((usx4*)xl)[i] = L;
    } else if (blk < 4352) {                // W_pos^T
        int f = blk - 4096;
        split_t_tile(W_pos, WposT_h, WposT_l, 512, 512, f & 15, f >> 4, tid, tile);
    } else if (blk < 5120) {                // W_qkv^T
        int f = blk - 4352;
        split_t_tile(W_qkv, WqkvT_h, WqkvT_l, 512, 1536, f % 48, f / 48, tid, tile);
    } else {                                // W_out^T
        int f = blk - 5120;
        split_t_tile(W_out, WoutT_h, WoutT_l, 512, 512, f & 15, f >> 4, tid, tile);
    }
}

// ---------------------------------------------------------------------------
// Kernel 2: split-bf16 MFMA GEMM.  C[M][N] = A[M][K] @ BT[N][K]^T
// Generic staging decode supports TM in {32,64,128}.
// MODE 0: fp32 C + bias.  MODE 1: hi/lo bf16 plane output.
// ---------------------------------------------------------------------------
template <int TM, int TN, int MODE>
__global__ __launch_bounds__(256) void gemm_bf3(
        const ushort_t* __restrict__ Ah, const ushort_t* __restrict__ Al,
        const ushort_t* __restrict__ Bh, const ushort_t* __restrict__ Bl,
        const float* __restrict__ bias, float* __restrict__ C,
        ushort_t* __restrict__ Ch, ushort_t* __restrict__ Cl,
        int M, int N, int K) {
    constexpr int NMI = TM / 32;
    constexpr int NNI = TN / 32;
    constexpr int NCH = (TM + TN) / 8;     // 64-cell (1 KB) chunks per k-iter

    __shared__ ushort_t lds[64 * (TM + TN)];

    const int tid = threadIdx.x;
    const int lane = tid & 63;
    const int w = tid >> 6;
    const int wm = w & 1, wn = w >> 1;
    const int c = lane & 15, quad = lane >> 4;
    const int m0 = blockIdx.y * TM;
    const int n0 = blockIdx.x * TN;

    f32x4 acc[NMI][NNI];
    #pragma unroll
    for (int mi = 0; mi < NMI; ++mi)
        #pragma unroll
        for (int ni = 0; ni < NNI; ++ni)
            acc[mi][ni] = (f32x4){0.f, 0.f, 0.f, 0.f};

    for (int k0 = 0; k0 < K; k0 += 32) {
        __syncthreads();
        #pragma unroll
        for (int ci = 0; ci < NCH / 4; ++ci) {
            int ch = ci * 4 + w;           // wave-uniform chunk id
            int cell = ch * 64 + lane;
            const ushort_t* src;
            if (cell < 8 * TM) {
                int plane = cell / (4 * TM);
                int rem = cell - plane * 4 * TM;
                int q = rem / TM, r = rem - q * TM;
                src = (plane ? Al : Ah) + (size_t)(m0 + r) * K + k0 + q * 8;
            } else {
                int cb = cell - 8 * TM;
                int plane = cb / (4 * TN);
                int rem = cb - plane * 4 * TN;
                int q = rem / TN, r = rem - q * TN;
                src = (plane ? Bl : Bh) + (size_t)(n0 + r) * K + k0 + q * 8;
            }
            gload16(src, &lds[(size_t)(ch * 64) * 8]);
        }
        __syncthreads();

        frag16 a_h[NMI], a_l[NMI], b_h[NNI], b_l[NNI];
        #pragma unroll
        for (int mi = 0; mi < NMI; ++mi) {
            int arow = wm * (TM / 2) + mi * 16 + c;
            a_h[mi] = *(const frag16*)&lds[((0 * 4 + quad) * TM + arow) * 8];
            a_l[mi] = *(const frag16*)&lds[((1 * 4 + quad) * TM + arow) * 8];
        }
        #pragma unroll
        for (int ni = 0; ni < NNI; ++ni) {
            int brow = wn * (TN / 2) + ni * 16 + c;
            b_h[ni] = *(const frag16*)&lds[(8 * TM + (0 * 4 + quad) * TN + brow) * 8];
            b_l[ni] = *(const frag16*)&lds[(8 * TM + (1 * 4 + quad) * TN + brow) * 8];
        }
        #pragma unroll
        for (int mi = 0; mi < NMI; ++mi)
            #pragma unroll
            for (int ni = 0; ni < NNI; ++ni) {
                acc[mi][ni] = MFMA16(a_h[mi], b_h[ni], acc[mi][ni], 0, 0, 0);
                acc[mi][ni] = MFMA16(a_h[mi], b_l[ni], acc[mi][ni], 0, 0, 0);
                acc[mi][ni] = MFMA16(a_l[mi], b_h[ni], acc[mi][ni], 0, 0, 0);
            }
    }

    #pragma unroll
    for (int mi = 0; mi < NMI; ++mi)
        #pragma unroll
        for (int ni = 0; ni < NNI; ++ni)
            #pragma unroll
            for (int reg = 0; reg < 4; ++reg) {
                int gm = m0 + wm * (TM / 2) + mi * 16 + quad * 4 + reg;
                int gn = n0 + wn * (TN / 2) + ni * 16 + c;
                float v = acc[mi][ni][reg];
                if (MODE == 0) {
                    C[(size_t)gm * N + gn] = v + bias[gn];
                } else {
                    ushort_t hh = f2bf(v);
                    Ch[(size_t)gm * N + gn] = hh;
                    Cl[(size_t)gm * N + gn] = f2bf(v - bf2f(hh));
                }
            }
}

// ---------------------------------------------------------------------------
// Kernel 3: V transpose: qkv planes' V section -> VT[b][h*64+d][t] planes.
// ---------------------------------------------------------------------------
__global__ __launch_bounds__(256) void vtrans_kernel(
        const ushort_t* __restrict__ qh, const ushort_t* __restrict__ ql,
        ushort_t* __restrict__ vth, ushort_t* __restrict__ vtl) {
    __shared__ ushort_t th[64][68], tl[64][68];
    int t0 = (blockIdx.x & 7) * 64;
    int n0 = ((blockIdx.x >> 3) & 7) * 64;
    int b  = blockIdx.x >> 6;
    int tid = threadIdx.x;
    {
        int tr = tid >> 2, nq = (tid & 3) * 16;
        size_t src = ((size_t)(t0 + tr) * BB + b) * (3 * DD) + 2 * DD + n0 + nq;
        *(frag16*)&th[tr][nq]     = *(const frag16*)&qh[src];
        *(frag16*)&th[tr][nq + 8] = *(const frag16*)&qh[src + 8];
        *(frag16*)&tl[tr][nq]     = *(const frag16*)&ql[src];
        *(frag16*)&tl[tr][nq + 8] = *(const frag16*)&ql[src + 8];
    }
    __syncthreads();
    {
        int nl = tid >> 2, tq = (tid & 3) * 16;
        union { frag16 v; ushort_t s[8]; } H0, H1, L0, L1;
        #pragma unroll
        for (int t = 0; t < 8; ++t) {
            H0.s[t] = th[tq + t][nl];     H1.s[t] = th[tq + 8 + t][nl];
            L0.s[t] = tl[tq + t][nl];     L1.s[t] = tl[tq + 8 + t][nl];
        }
        size_t dst = ((size_t)b * DD + n0 + nl) * TT + t0 + tq;
        *(frag16*)&vth[dst]     = H0.v;
        *(frag16*)&vth[dst + 8] = H1.v;
        *(frag16*)&vtl[dst]     = L0.v;
        *(frag16*)&vtl[dst + 8] = L1.v;
    }
}

// ---------------------------------------------------------------------------
// Kernel 4: fused flash attention, split-bf16 MFMA.
// Block = (64 i-rows, b, h); 4 waves x 16 i-rows, private online softmax.
// Circular 128-row P window (64 new rows per j-tile after the first).
// p stored as single bf16 plane; l accumulated from the ROUNDED p values,
// so O/l stays an exact convex combination (no lo-plane needed).
// ---------------------------------------------------------------------------
#define PSTR 72

struct WU {
    union {
        float    qp[16][81];
        ushort_t p[16][PSTR];
    };
};

__global__ __launch_bounds__(256, 2) void attn_kernel(
        const ushort_t* __restrict__ qkv_h, const ushort_t* __restrict__ qkv_l,
        const ushort_t* __restrict__ T_h, const ushort_t* __restrict__ T_l,
        const ushort_t* __restrict__ vt_h, const ushort_t* __restrict__ vt_l,
        const float* __restrict__ pos_u, const float* __restrict__ pos_v,
        const float* __restrict__ tau,
        ushort_t* __restrict__ o_h, ushort_t* __restrict__ o_l) {
    const int i0 = blockIdx.x * 64;
    const int b  = blockIdx.y;
    const int h  = blockIdx.z;
    const int tid  = threadIdx.x;
    const int lane = tid & 63;
    const int w    = tid >> 6;
    const int c    = lane & 15;
    const int quad = lane >> 4;

    __shared__ __align__(16) ushort_t K_hi[64][PSTR], K_lo[64][PSTR];  // K then V^T
    __shared__ __align__(16) ushort_t P_hi[128][PSTR], P_lo[128][PSTR];
    __shared__ __align__(16) WU wbuf[4];

    const float tauexp = expf(tau[0]);
    const float scale  = 0.125f;
    const float NEGMAX = -3.4028234663852886e38f;

    // ---- persistent q fragments (qu = q+u, qv = q+v), hi/lo split ----
    frag16 qu_h[2], qu_l[2], qv_h[2], qv_l[2];
    {
        int row = i0 + w * 16 + c;
        size_t base = ((size_t)row * BB + b) * (3 * DD) + h * DHH;
        const float* up = pos_u + h * DHH;
        const float* vp = pos_v + h * DHH;
        #pragma unroll
        for (int kb = 0; kb < 2; ++kb) {
            int d0 = kb * 32 + quad * 8;
            union { frag16 v; ushort_t s[8]; } QH, QL, UH, UL, VH, VL;
            QH.v = *(const frag16*)&qkv_h[base + d0];
            QL.v = *(const frag16*)&qkv_l[base + d0];
            #pragma unroll
            for (int t = 0; t < 8; ++t) {
                float q = bf2f(QH.s[t]) + bf2f(QL.s[t]);
                float a = q + up[d0 + t];
                ushort_t ah = f2bf(a);
                UH.s[t] = ah; UL.s[t] = f2bf(a - bf2f(ah));
                float bq = q + vp[d0 + t];
                ushort_t bh = f2bf(bq);
                VH.s[t] = bh; VL.s[t] = f2bf(bq - bf2f(bh));
            }
            qu_h[kb] = UH.v; qu_l[kb] = UL.v;
            qv_h[kb] = VH.v; qv_l[kb] = VL.v;
        }
    }

    float m_r[4], l_r[4];
    f32x4 o_acc[4];
    #pragma unroll
    for (int r = 0; r < 4; ++r) { m_r[r] = NEGMAX; l_r[r] = 0.f; }
    #pragma unroll
    for (int d = 0; d < 4; ++d) o_acc[d] = (f32x4){0.f, 0.f, 0.f, 0.f};

    for (int jt = 0; jt < 8; ++jt) {
        const int j0  = jt * 64;
        const int rlo = i0 - j0 + 448;     // window = table rows [rlo, rlo+128)

        __syncthreads();

        // stage K tile (64 x 64), both planes
        {
            int j = tid >> 2, d0 = (tid & 3) * 16;
            size_t kb2 = ((size_t)(j0 + j) * BB + b) * (3 * DD) + DD + h * DHH + d0;
            *(frag16*)&K_hi[j][d0]     = *(const frag16*)&qkv_h[kb2];
            *(frag16*)&K_hi[j][d0 + 8] = *(const frag16*)&qkv_h[kb2 + 8];
            *(frag16*)&K_lo[j][d0]     = *(const frag16*)&qkv_l[kb2];
            *(frag16*)&K_lo[j][d0 + 8] = *(const frag16*)&qkv_l[kb2 + 8];
        }
        // stage P window: full 128 rows at jt=0, 64 new rows after
        if (jt == 0) {
            int r = tid >> 1, d0 = (tid & 1) * 32;
            int rg = rlo + r, slot = rg & 127;
            size_t tb = (size_t)rg * DD + h * DHH + d0;
            #pragma unroll
            for (int g = 0; g < 4; ++g) {
                *(frag16*)&P_hi[slot][d0 + g * 8] = *(const frag16*)&T_h[tb + g * 8];
                *(frag16*)&P_lo[slot][d0 + g * 8] = *(const frag16*)&T_l[tb + g * 8];
            }
        } else {
            int r = tid >> 2, d0 = (tid & 3) * 16;
            int rg = rlo + r, slot = rg & 127;
            size_t tb = (size_t)rg * DD + h * DHH + d0;
            *(frag16*)&P_hi[slot][d0]     = *(const frag16*)&T_h[tb];
            *(frag16*)&P_hi[slot][d0 + 8] = *(const frag16*)&T_h[tb + 8];
            *(frag16*)&P_lo[slot][d0]     = *(const frag16*)&T_l[tb];
            *(frag16*)&P_lo[slot][d0 + 8] = *(const frag16*)&T_l[tb + 8];
        }
        __syncthreads();

        // ---- QP = qv @ P_band^T (16 x 80) -> per-wave LDS ----
        f32x4 qp_acc[5];
        #pragma unroll
        for (int rs = 0; rs < 5; ++rs) {
            f32x4 acc = (f32x4){0.f, 0.f, 0.f, 0.f};
            int slot = (rlo + w * 16 + rs * 16 + c) & 127;
            #pragma unroll
            for (int kb = 0; kb < 2; ++kb) {
                frag16 ph = *(const frag16*)&P_hi[slot][kb * 32 + quad * 8];
                frag16 pl = *(const frag16*)&P_lo[slot][kb * 32 + quad * 8];
                acc = MFMA16(qv_h[kb], ph, acc, 0, 0, 0);
                acc = MFMA16(qv_h[kb], pl, acc, 0, 0, 0);
                acc = MFMA16(qv_l[kb], ph, acc, 0, 0, 0);
            }
            qp_acc[rs] = acc;
        }
        #pragma unroll
        for (int rs = 0; rs < 5; ++rs)
            #pragma unroll
            for (int reg = 0; reg < 4; ++reg)
                wbuf[w].qp[quad * 4 + reg][rs * 16 + c] = qp_acc[rs][reg];

        // ---- AC = qu @ K^T (16 x 64) ----
        f32x4 ac[4];
        #pragma unroll
        for (int js = 0; js < 4; ++js) {
            f32x4 acc = (f32x4){0.f, 0.f, 0.f, 0.f};
            int krow = js * 16 + c;
            #pragma unroll
            for (int kb = 0; kb < 2; ++kb) {
                frag16 kh = *(const frag16*)&K_hi[krow][kb * 32 + quad * 8];
                frag16 kl = *(const frag16*)&K_lo[krow][kb * 32 + quad * 8];
                acc = MFMA16(qu_h[kb], kh, acc, 0, 0, 0);
                acc = MFMA16(qu_h[kb], kl, acc, 0, 0, 0);
                acc = MFMA16(qu_l[kb], kh, acc, 0, 0, 0);
            }
            ac[js] = acc;
        }

        // ---- energy assembly ----
        float ev[4][4];
        #pragma unroll
        for (int js = 0; js < 4; ++js) {
            int jl = js * 16 + c;
            #pragma unroll
            for (int reg = 0; reg < 4; ++reg) {
                int il = quad * 4 + reg;
                float bd = wbuf[w].qp[il][il - jl + 63];
                float e = (ac[js][reg] + bd) * scale;
                if (i0 + w * 16 + il == j0 + jl) e = NEGMAX;
                ev[js][reg] = e * tauexp;
            }
        }

        // ---- online softmax; p stored single-plane, l from rounded p ----
        float alpha[4], mn[4];
        #pragma unroll
        for (int reg = 0; reg < 4; ++reg) {
            float mx = fmaxf(fmaxf(ev[0][reg], ev[1][reg]),
                             fmaxf(ev[2][reg], ev[3][reg]));
            #pragma unroll
            for (int m = 1; m < 16; m <<= 1) mx = fmaxf(mx, __shfl_xor(mx, m));
            float m2 = fmaxf(m_r[reg], mx);
            alpha[reg] = __expf(m_r[reg] - m2);
            mn[reg] = m2;
            m_r[reg] = m2;
        }
        float ss[4] = {0.f, 0.f, 0.f, 0.f};
        #pragma unroll
        for (int js = 0; js < 4; ++js) {
            int jl = js * 16 + c;
            #pragma unroll
            for (int reg = 0; reg < 4; ++reg) {
                float p = __expf(ev[js][reg] - mn[reg]);
                ushort_t ph = f2bf(p);
                ss[reg] += bf2f(ph);          // exact-l: sum the rounded weights
                wbuf[w].p[quad * 4 + reg][jl] = ph;
            }
        }
        #pragma unroll
        for (int reg = 0; reg < 4; ++reg) {
            float s = ss[reg];
            #pragma unroll
            for (int m = 1; m < 16; m <<= 1) s += __shfl_xor(s, m);
            l_r[reg] = l_r[reg] * alpha[reg] + s;
        }

        __syncthreads();
        // stage V^T (pre-transposed in global) into K buffer, vector copies
        {
            int d = tid >> 2, jq = (tid & 3) * 16;
            size_t vb = ((size_t)b * DD + h * DHH + d) * TT + j0 + jq;
            *(frag16*)&K_hi[d][jq]     = *(const frag16*)&vt_h[vb];
            *(frag16*)&K_hi[d][jq + 8] = *(const frag16*)&vt_h[vb + 8];
            *(frag16*)&K_lo[d][jq]     = *(const frag16*)&vt_l[vb];
            *(frag16*)&K_lo[d][jq + 8] = *(const frag16*)&vt_l[vb + 8];
        }
        __syncthreads();

        // ---- O = O*alpha + p @ V (2 products: p*vh + p*vl) ----
        frag16 pf[2];
        #pragma unroll
        for (int kb = 0; kb < 2; ++kb)
            pf[kb] = *(const frag16*)&wbuf[w].p[c][kb * 32 + quad * 8];
        #pragma unroll
        for (int ds = 0; ds < 4; ++ds) {
            f32x4 acc = o_acc[ds];
            #pragma unroll
            for (int reg = 0; reg < 4; ++reg) acc[reg] *= alpha[reg];
            #pragma unroll
            for (int kb = 0; kb < 2; ++kb) {
                frag16 vh = *(const frag16*)&K_hi[ds * 16 + c][kb * 32 + quad * 8];
                frag16 vl = *(const frag16*)&K_lo[ds * 16 + c][kb * 32 + quad * 8];
                acc = MFMA16(pf[kb], vh, acc, 0, 0, 0);
                acc = MFMA16(pf[kb], vl, acc, 0, 0, 0);
            }
            o_acc[ds] = acc;
        }
    }

    // ---- epilogue: normalize, split, store planes ----
    #pragma unroll
    for (int ds = 0; ds < 4; ++ds)
        #pragma unroll
        for (int reg = 0; reg < 4; ++reg) {
            int row = i0 + w * 16 + quad * 4 + reg;
            size_t idx = ((size_t)row * BB + b) * DD + h * DHH + ds * 16 + c;
            float val = o_acc[ds][reg] / l_r[reg];
            ushort_t hh = f2bf(val);
            o_h[idx] = hh;
            o_l[idx] = f2bf(val - bf2f(hh));
        }
}

// ---------------------------------------------------------------------------
// launch
// ---------------------------------------------------------------------------
extern "C" void kernel_launch(void* const* d_in, const int* in_sizes, int n_in,
                              void* d_out, int out_size, void* d_ws, size_t ws_size,
                              hipStream_t stream) {
    const float* x     = (const float*)d_in[0];
    const float* W_qkv = (const float*)d_in[1];
    const float* W_pos = (const float*)d_in[2];
    const float* pos_u = (const float*)d_in[3];
    const float* pos_v = (const float*)d_in[4];
    const float* W_out = (const float*)d_in[5];
    const float* b_out = (const float*)d_in[6];
    const float* tau   = (const float*)d_in[7];
    float* out = (float*)d_out;

    ushort_t* p = (ushort_t*)d_ws;
    ushort_t* feat_h  = p; p += 1024 * 512;
    ushort_t* feat_l  = p; p += 1024 * 512;
    ushort_t* WposT_h = p; p += 512 * 512;
    ushort_t* WposT_l = p; p += 512 * 512;
    ushort_t* table_h = p; p += 1024 * 512;
    ushort_t* table_l = p; p += 1024 * 512;
    ushort_t* x_h     = p; p += 4096 * 512;   // reused as VT_h after qkv GEMM
    ushort_t* x_l     = p; p += 4096 * 512;   // reused as VT_l
    ushort_t* WqkvT_h = p; p += 1536 * 512;
    ushort_t* WqkvT_l = p; p += 1536 * 512;
    ushort_t* qkv_h   = p; p += 4096 * 1536;
    ushort_t* qkv_l   = p; p += 4096 * 1536;
    ushort_t* WoutT_h = p; p += 512 * 512;
    ushort_t* WoutT_l = p; p += 512 * 512;
    ushort_t* ao_h    = p; p += 4096 * 512;
    ushort_t* ao_l    = p; p += 4096 * 512;
    ushort_t* vt_h = x_h;                     // x planes dead after qkv GEMM
    ushort_t* vt_l = x_l;

    // 1. all input prep in one launch
    prep_kernel<<<5376, 256, 0, stream>>>(
        x, W_pos, W_qkv, W_out, feat_h, feat_l, x_h, x_l,
        WposT_h, WposT_l, WqkvT_h, WqkvT_l, WoutT_h, WoutT_l);
    // 2. table = feat @ W_pos  (1024 x 512 x 512)
    gemm_bf3<32, 64, 1><<<dim3(512 / 64, 1024 / 32), 256, 0, stream>>>(
        feat_h, feat_l, WposT_h, WposT_l, nullptr, nullptr, table_h, table_l,
        1024, 512, 512);
    // 3. qkv = x @ W_qkv  (4096 x 1536 x 512)
    gemm_bf3<128, 128, 1><<<dim3(1536 / 128, 4096 / 128), 256, 0, stream>>>(
        x_h, x_l, WqkvT_h, WqkvT_l, nullptr, nullptr, qkv_h, qkv_l,
        4096, 1536, 512);
    // 4. V transpose (overwrites x planes)
    vtrans_kernel<<<512, 256, 0, stream>>>(qkv_h, qkv_l, vt_h, vt_l);
    // 5. fused attention -> attno planes
    attn_kernel<<<dim3(8, 8, 8), 256, 0, stream>>>(
        qkv_h, qkv_l, table_h, table_l, vt_h, vt_l, pos_u, pos_v, tau,
        ao_h, ao_l);
    // 6. out = attno @ W_out + b_out  (4096 x 512 x 512)
    gemm_bf3<64, 128, 0><<<dim3(512 / 128, 4096 / 64), 256, 0, stream>>>(
        ao_h, ao_l, WoutT_h, WoutT_l, b_out, out, nullptr, nullptr,
        4096, 512, 512);
}

// Round 6
// 187.634 us; speedup vs baseline: 4.7857x; 1.0823x over previous
//
#include <hip/hip_runtime.h>
#include <hip/hip_bf16.h>

// Problem constants: T=512, B=8, D=512, H=8, DH=64
#define TT 512
#define BB 8
#define DD 512
#define HH 8
#define DHH 64

typedef unsigned short ushort_t;
using frag16 = __attribute__((ext_vector_type(8))) short;     // 8 bf16
using f32x4  = __attribute__((ext_vector_type(4))) float;     // MFMA acc
using usx4   = __attribute__((ext_vector_type(4))) ushort_t;  // 4 bf16

#define MFMA16 __builtin_amdgcn_mfma_f32_16x16x32_bf16

__device__ inline ushort_t f2bf(float x) {
    __hip_bfloat16 h = __float2bfloat16(x);
    ushort_t u; __builtin_memcpy(&u, &h, 2); return u;
}
__device__ inline float bf2f(ushort_t u) {
    __hip_bfloat16 h; __builtin_memcpy(&h, &u, 2);
    return __bfloat162float(h);
}

// async global->LDS DMA, 16 B/lane; lds dest = wave-uniform base + lane*16
__device__ inline void gload16(const void* g, void* l) {
    __builtin_amdgcn_global_load_lds(
        (const __attribute__((address_space(1))) unsigned int*)g,
        (__attribute__((address_space(3))) unsigned int*)l, 16, 0, 0);
}

// ---------------------------------------------------------------------------
// Kernel 1: fused input prep (feat planes, x split, W transpose+split).
// ---------------------------------------------------------------------------
__device__ inline void split_t_tile(const float* __restrict__ in,
                                    ushort_t* __restrict__ oh,
                                    ushort_t* __restrict__ ol,
                                    int K, int N, int bx, int by, int tid,
                                    float (*tile)[33]) {
    int n0 = bx * 32, k0 = by * 32;
    {
        int r = tid >> 3, c0 = (tid & 7) * 4;
        float4 v = *(const float4*)&in[(size_t)(k0 + r) * N + n0 + c0];
        tile[r][c0] = v.x; tile[r][c0 + 1] = v.y;
        tile[r][c0 + 2] = v.z; tile[r][c0 + 3] = v.w;
    }
    __syncthreads();
    {
        int n = tid >> 3, kk = (tid & 7) * 4;
        usx4 H, L;
        #pragma unroll
        for (int t = 0; t < 4; ++t) {
            float x = tile[kk + t][n];
            ushort_t hh = f2bf(x);
            H[t] = hh;
            L[t] = f2bf(x - bf2f(hh));
        }
        *(usx4*)&oh[(size_t)(n0 + n) * K + k0 + kk] = H;
        *(usx4*)&ol[(size_t)(n0 + n) * K + k0 + kk] = L;
    }
}

__global__ __launch_bounds__(256) void prep_kernel(
        const float* __restrict__ x, const float* __restrict__ W_pos,
        const float* __restrict__ W_qkv, const float* __restrict__ W_out,
        ushort_t* __restrict__ fh, ushort_t* __restrict__ fl,
        ushort_t* __restrict__ xh, ushort_t* __restrict__ xl,
        ushort_t* __restrict__ WposT_h, ushort_t* __restrict__ WposT_l,
        ushort_t* __restrict__ WqkvT_h, ushort_t* __restrict__ WqkvT_l,
        ushort_t* __restrict__ WoutT_h, ushort_t* __restrict__ WoutT_l) {
    __shared__ float tile[32][33];
    int blk = blockIdx.x;
    int tid = threadIdx.x;
    if (blk < 2048) {                       // feat
        int idx = blk * 256 + tid;
        int r = idx >> 9, c = idx & 511;
        float dist = (float)(r - 511);
        int cc = c & 255;
        float freq = expf((-logf(10000.0f) * (float)cc) / 256.0f);
        float ang = dist * freq;
        float v = (c < 256) ? sinf(ang) : cosf(ang);
        ushort_t hh = f2bf(v);
        fh[idx] = hh;
        fl[idx] = f2bf(v - bf2f(hh));
    } else if (blk < 4096) {                // split x (4 elems/thread)
        int i = (blk - 2048) * 256 + tid;
        float4 v = ((const float4*)x)[i];
        float e[4] = {v.x, v.y, v.z, v.w};
        usx4 H, L;
        #pragma unroll
        for (int t = 0; t < 4; ++t) {
            ushort_t hh = f2bf(e[t]);
            H[t] = hh;
            L[t] = f2bf(e[t] - bf2f(hh));
        }
        ((usx4*)xh)[i] = H;
        ((usx4*)xl)[i] = L;
    } else if (blk < 4352) {                // W_pos^T
        int f = blk - 4096;
        split_t_tile(W_pos, WposT_h, WposT_l, 512, 512, f & 15, f >> 4, tid, tile);
    } else if (blk < 5120) {                // W_qkv^T
        int f = blk - 4352;
        split_t_tile(W_qkv, WqkvT_h, WqkvT_l, 512, 1536, f % 48, f / 48, tid, tile);
    } else {                                // W_out^T
        int f = blk - 5120;
        split_t_tile(W_out, WoutT_h, WoutT_l, 512, 512, f & 15, f >> 4, tid, tile);
    }
}

// ---------------------------------------------------------------------------
// Kernel 2 (device core): split-bf16 MFMA GEMM.  C = A @ BT^T
// MODE 0: fp32 C + bias.  MODE 1: hi/lo plane output.  MODE 2: hi plane only.
// ---------------------------------------------------------------------------
template <int TM, int TN, int MODE>
__device__ void gemm_bf3_dev(
        ushort_t* lds, int bx, int by,
        const ushort_t* __restrict__ Ah, const ushort_t* __restrict__ Al,
        const ushort_t* __restrict__ Bh, const ushort_t* __restrict__ Bl,
        const float* __restrict__ bias, float* __restrict__ C,
        ushort_t* __restrict__ Ch, ushort_t* __restrict__ Cl,
        int M, int N, int K) {
    constexpr int NMI = TM / 32;
    constexpr int NNI = TN / 32;
    constexpr int NCH = (TM + TN) / 8;

    const int tid = threadIdx.x;
    const int lane = tid & 63;
    const int w = tid >> 6;
    const int wm = w & 1, wn = w >> 1;
    const int c = lane & 15, quad = lane >> 4;
    const int m0 = by * TM;
    const int n0 = bx * TN;

    f32x4 acc[NMI][NNI];
    #pragma unroll
    for (int mi = 0; mi < NMI; ++mi)
        #pragma unroll
        for (int ni = 0; ni < NNI; ++ni)
            acc[mi][ni] = (f32x4){0.f, 0.f, 0.f, 0.f};

    for (int k0 = 0; k0 < K; k0 += 32) {
        __syncthreads();
        #pragma unroll
        for (int ci = 0; ci < NCH / 4; ++ci) {
            int ch = ci * 4 + w;
            int cell = ch * 64 + lane;
            const ushort_t* src;
            if (cell < 8 * TM) {
                int plane = cell / (4 * TM);
                int rem = cell - plane * 4 * TM;
                int q = rem / TM, r = rem - q * TM;
                src = (plane ? Al : Ah) + (size_t)(m0 + r) * K + k0 + q * 8;
            } else {
                int cb = cell - 8 * TM;
                int plane = cb / (4 * TN);
                int rem = cb - plane * 4 * TN;
                int q = rem / TN, r = rem - q * TN;
                src = (plane ? Bl : Bh) + (size_t)(n0 + r) * K + k0 + q * 8;
            }
            gload16(src, &lds[(size_t)(ch * 64) * 8]);
        }
        __syncthreads();

        frag16 a_h[NMI], a_l[NMI], b_h[NNI], b_l[NNI];
        #pragma unroll
        for (int mi = 0; mi < NMI; ++mi) {
            int arow = wm * (TM / 2) + mi * 16 + c;
            a_h[mi] = *(const frag16*)&lds[((0 * 4 + quad) * TM + arow) * 8];
            a_l[mi] = *(const frag16*)&lds[((1 * 4 + quad) * TM + arow) * 8];
        }
        #pragma unroll
        for (int ni = 0; ni < NNI; ++ni) {
            int brow = wn * (TN / 2) + ni * 16 + c;
            b_h[ni] = *(const frag16*)&lds[(8 * TM + (0 * 4 + quad) * TN + brow) * 8];
            b_l[ni] = *(const frag16*)&lds[(8 * TM + (1 * 4 + quad) * TN + brow) * 8];
        }
        #pragma unroll
        for (int mi = 0; mi < NMI; ++mi)
            #pragma unroll
            for (int ni = 0; ni < NNI; ++ni) {
                acc[mi][ni] = MFMA16(a_h[mi], b_h[ni], acc[mi][ni], 0, 0, 0);
                acc[mi][ni] = MFMA16(a_h[mi], b_l[ni], acc[mi][ni], 0, 0, 0);
                acc[mi][ni] = MFMA16(a_l[mi], b_h[ni], acc[mi][ni], 0, 0, 0);
            }
    }

    #pragma unroll
    for (int mi = 0; mi < NMI; ++mi)
        #pragma unroll
        for (int ni = 0; ni < NNI; ++ni)
            #pragma unroll
            for (int reg = 0; reg < 4; ++reg) {
                int gm = m0 + wm * (TM / 2) + mi * 16 + quad * 4 + reg;
                int gn = n0 + wn * (TN / 2) + ni * 16 + c;
                float v = acc[mi][ni][reg];
                if (MODE == 0) {
                    C[(size_t)gm * N + gn] = v + bias[gn];
                } else {
                    ushort_t hh = f2bf(v);
                    Ch[(size_t)gm * N + gn] = hh;
                    if (MODE == 1)
                        Cl[(size_t)gm * N + gn] = f2bf(v - bf2f(hh));
                }
            }
}

template <int TM, int TN, int MODE>
__global__ __launch_bounds__(256) void gemm_bf3(
        const ushort_t* __restrict__ Ah, const ushort_t* __restrict__ Al,
        const ushort_t* __restrict__ Bh, const ushort_t* __restrict__ Bl,
        const float* __restrict__ bias, float* __restrict__ C,
        ushort_t* __restrict__ Ch, ushort_t* __restrict__ Cl,
        int M, int N, int K) {
    __shared__ __align__(16) ushort_t lds[64 * (TM + TN)];
    gemm_bf3_dev<TM, TN, MODE>(lds, blockIdx.x, blockIdx.y,
                               Ah, Al, Bh, Bl, bias, C, Ch, Cl, M, N, K);
}

// ---------------------------------------------------------------------------
// Kernel 3 (device core): V transpose -> VT[b][h*64+d][t] planes.
// ---------------------------------------------------------------------------
__device__ void vtrans_dev(ushort_t* lds, int blk,
                           const ushort_t* __restrict__ qh,
                           const ushort_t* __restrict__ ql,
                           ushort_t* __restrict__ vth,
                           ushort_t* __restrict__ vtl) {
    ushort_t (*th)[68] = (ushort_t(*)[68])lds;
    ushort_t (*tl)[68] = (ushort_t(*)[68])(lds + 64 * 68);
    int t0 = (blk & 7) * 64;
    int n0 = ((blk >> 3) & 7) * 64;
    int b  = blk >> 6;
    int tid = threadIdx.x;
    {
        int tr = tid >> 2, nq = (tid & 3) * 16;
        size_t src = ((size_t)(t0 + tr) * BB + b) * (3 * DD) + 2 * DD + n0 + nq;
        *(frag16*)&th[tr][nq]     = *(const frag16*)&qh[src];
        *(frag16*)&th[tr][nq + 8] = *(const frag16*)&qh[src + 8];
        *(frag16*)&tl[tr][nq]     = *(const frag16*)&ql[src];
        *(frag16*)&tl[tr][nq + 8] = *(const frag16*)&ql[src + 8];
    }
    __syncthreads();
    {
        int nl = tid >> 2, tq = (tid & 3) * 16;
        union { frag16 v; ushort_t s[8]; } H0, H1, L0, L1;
        #pragma unroll
        for (int t = 0; t < 8; ++t) {
            H0.s[t] = th[tq + t][nl];     H1.s[t] = th[tq + 8 + t][nl];
            L0.s[t] = tl[tq + t][nl];     L1.s[t] = tl[tq + 8 + t][nl];
        }
        size_t dst = ((size_t)b * DD + n0 + nl) * TT + t0 + tq;
        *(frag16*)&vth[dst]     = H0.v;
        *(frag16*)&vth[dst + 8] = H1.v;
        *(frag16*)&vtl[dst]     = L0.v;
        *(frag16*)&vtl[dst + 8] = L1.v;
    }
}

// fused: table GEMM (256 blocks) + vtrans (512 blocks)
__global__ __launch_bounds__(256) void l3_kernel(
        const ushort_t* __restrict__ feat_h, const ushort_t* __restrict__ feat_l,
        const ushort_t* __restrict__ WposT_h, const ushort_t* __restrict__ WposT_l,
        ushort_t* __restrict__ table_h,
        const ushort_t* __restrict__ qkv_h, const ushort_t* __restrict__ qkv_l,
        ushort_t* __restrict__ vt_h, ushort_t* __restrict__ vt_l) {
    __shared__ __align__(16) ushort_t lds[2 * 64 * 68];   // 8704 us >= 6144
    int blk = blockIdx.x;
    if (blk < 256) {
        gemm_bf3_dev<32, 64, 2>(lds, blk & 7, blk >> 3,
                                feat_h, feat_l, WposT_h, WposT_l,
                                nullptr, nullptr, table_h, nullptr,
                                1024, 512, 512);
    } else {
        vtrans_dev(lds, blk - 256, qkv_h, qkv_l, vt_h, vt_l);
    }
}

// ---------------------------------------------------------------------------
// Kernel 4: fused flash attention, split-bf16 MFMA.
// Block = (b, 64 i-rows, h): grid order makes XCD = b (K/V L2-resident).
// K/V/P staged via global_load_lds into XOR-swizzled unpadded LDS:
//   layout chunk(plane,row,cl) = (plane*64+row)*8 + (cl ^ (row&7)), 16B chunks.
//   Staging: lane l -> chunk base+l, source chunk (l&7)^(l>>3) of row l>>3.
//   Frag reads: bank group (kb*4+quad)^(c&7) -> 2 lanes/group = conflict-free.
// P single plane (BD = qv . bf16(P), 2 MFMA products).
// LDS = 52.3 KB -> 3 blocks/CU.
// ---------------------------------------------------------------------------
struct WU {
    union {
        float    qp[16][81];   // QP gather tile (odd stride: conflict-free)
        ushort_t p[16][72];    // softmax weights (16B-aligned rows)
    };
};

__global__ __launch_bounds__(256, 3) void attn_kernel(
        const ushort_t* __restrict__ qkv_h, const ushort_t* __restrict__ qkv_l,
        const ushort_t* __restrict__ T_h,
        const ushort_t* __restrict__ vt_h, const ushort_t* __restrict__ vt_l,
        const float* __restrict__ pos_u, const float* __restrict__ pos_v,
        const float* __restrict__ tau,
        ushort_t* __restrict__ o_h, ushort_t* __restrict__ o_l) {
    const int b  = blockIdx.x;
    const int i0 = blockIdx.y * 64;
    const int h  = blockIdx.z;
    const int tid  = threadIdx.x;
    const int lane = tid & 63;
    const int w    = tid >> 6;
    const int c    = lane & 15;
    const int quad = lane >> 4;

    __shared__ __align__(16) ushort_t Kbuf[8192];   // 2 planes x 64 rows (K, then V^T)
    __shared__ __align__(16) ushort_t Pbuf[8192];   // 128-slot circular window, hi only
    __shared__ __align__(16) WU wbuf[4];

    const int chl = (lane & 7) ^ (lane >> 3);       // staging source chunk
    const int rql = lane >> 3;                      // staging row offset
    const int swz0 = quad ^ (c & 7);                // frag chunk, kb=0
    const int swz1 = (4 + quad) ^ (c & 7);          // frag chunk, kb=1

    const float tauexp = expf(tau[0]);
    const float scale  = 0.125f;
    const float NEGMAX = -3.4028234663852886e38f;

    // ---- persistent q fragments (qu = q+u, qv = q+v), hi/lo split ----
    frag16 qu_h[2], qu_l[2], qv_h[2], qv_l[2];
    {
        int row = i0 + w * 16 + c;
        size_t base = ((size_t)row * BB + b) * (3 * DD) + h * DHH;
        const float* up = pos_u + h * DHH;
        const float* vp = pos_v + h * DHH;
        #pragma unroll
        for (int kb = 0; kb < 2; ++kb) {
            int d0 = kb * 32 + quad * 8;
            union { frag16 v; ushort_t s[8]; } QH, QL, UH, UL, VH, VL;
            QH.v = *(const frag16*)&qkv_h[base + d0];
            QL.v = *(const frag16*)&qkv_l[base + d0];
            #pragma unroll
            for (int t = 0; t < 8; ++t) {
                float q = bf2f(QH.s[t]) + bf2f(QL.s[t]);
                float a = q + up[d0 + t];
                ushort_t ah = f2bf(a);
                UH.s[t] = ah; UL.s[t] = f2bf(a - bf2f(ah));
                float bq = q + vp[d0 + t];
                ushort_t bh = f2bf(bq);
                VH.s[t] = bh; VL.s[t] = f2bf(bq - bf2f(bh));
            }
            qu_h[kb] = UH.v; qu_l[kb] = UL.v;
            qv_h[kb] = VH.v; qv_l[kb] = VL.v;
        }
    }

    float m_r[4], l_r[4];
    f32x4 o_acc[4];
    #pragma unroll
    for (int r = 0; r < 4; ++r) { m_r[r] = NEGMAX; l_r[r] = 0.f; }
    #pragma unroll
    for (int d = 0; d < 4; ++d) o_acc[d] = (f32x4){0.f, 0.f, 0.f, 0.f};

    for (int jt = 0; jt < 8; ++jt) {
        const int j0  = jt * 64;
        const int rlo = i0 - j0 + 448;     // window = table rows [rlo, rlo+128)

        __syncthreads();

        // stage K (2 planes x 64 rows): 16 DMA issues, 4 per wave
        #pragma unroll
        for (int it = 0; it < 4; ++it) {
            int iss = it * 4 + w;
            int pl = iss >> 3, r0 = (iss & 7) * 8;
            int row = r0 + rql;
            const ushort_t* src = (pl ? qkv_l : qkv_h)
                + ((size_t)(j0 + row) * BB + b) * (3 * DD) + DD + h * DHH + chl * 8;
            gload16(src, &Kbuf[(pl * 64 + r0) * 64]);
        }
        // stage P window: 128 rows at jt=0, 64 new rows after
        if (jt == 0) {
            #pragma unroll
            for (int it = 0; it < 4; ++it) {
                int r0 = (it * 4 + w) * 8;
                int sbase = (rlo + r0) & 127;
                const ushort_t* src = T_h + (size_t)(rlo + r0 + rql) * DD + h * DHH + chl * 8;
                gload16(src, &Pbuf[sbase * 64]);
            }
        } else {
            #pragma unroll
            for (int it = 0; it < 2; ++it) {
                int r0 = (it * 4 + w) * 8;
                int sbase = (rlo + r0) & 127;
                const ushort_t* src = T_h + (size_t)(rlo + r0 + rql) * DD + h * DHH + chl * 8;
                gload16(src, &Pbuf[sbase * 64]);
            }
        }
        __syncthreads();

        // ---- QP = qv @ P_band^T (16 x 80): 2 products -> per-wave LDS ----
        f32x4 qp_acc[5];
        #pragma unroll
        for (int rs = 0; rs < 5; ++rs) {
            f32x4 acc = (f32x4){0.f, 0.f, 0.f, 0.f};
            int slot = (rlo + w * 16 + rs * 16 + c) & 127;
            frag16 p0 = *(const frag16*)&Pbuf[slot * 64 + swz0 * 8];
            frag16 p1 = *(const frag16*)&Pbuf[slot * 64 + swz1 * 8];
            acc = MFMA16(qv_h[0], p0, acc, 0, 0, 0);
            acc = MFMA16(qv_l[0], p0, acc, 0, 0, 0);
            acc = MFMA16(qv_h[1], p1, acc, 0, 0, 0);
            acc = MFMA16(qv_l[1], p1, acc, 0, 0, 0);
            qp_acc[rs] = acc;
        }
        #pragma unroll
        for (int rs = 0; rs < 5; ++rs)
            #pragma unroll
            for (int reg = 0; reg < 4; ++reg)
                wbuf[w].qp[quad * 4 + reg][rs * 16 + c] = qp_acc[rs][reg];

        // ---- AC = qu @ K^T (16 x 64): 3 products ----
        f32x4 ac[4];
        #pragma unroll
        for (int js = 0; js < 4; ++js) {
            f32x4 acc = (f32x4){0.f, 0.f, 0.f, 0.f};
            int krow = js * 16 + c;
            frag16 kh0 = *(const frag16*)&Kbuf[krow * 64 + swz0 * 8];
            frag16 kh1 = *(const frag16*)&Kbuf[krow * 64 + swz1 * 8];
            frag16 kl0 = *(const frag16*)&Kbuf[4096 + krow * 64 + swz0 * 8];
            frag16 kl1 = *(const frag16*)&Kbuf[4096 + krow * 64 + swz1 * 8];
            acc = MFMA16(qu_h[0], kh0, acc, 0, 0, 0);
            acc = MFMA16(qu_h[0], kl0, acc, 0, 0, 0);
            acc = MFMA16(qu_l[0], kh0, acc, 0, 0, 0);
            acc = MFMA16(qu_h[1], kh1, acc, 0, 0, 0);
            acc = MFMA16(qu_h[1], kl1, acc, 0, 0, 0);
            acc = MFMA16(qu_l[1], kh1, acc, 0, 0, 0);
            ac[js] = acc;
        }

        // ---- energy assembly ----
        float ev[4][4];
        #pragma unroll
        for (int js = 0; js < 4; ++js) {
            int jl = js * 16 + c;
            #pragma unroll
            for (int reg = 0; reg < 4; ++reg) {
                int il = quad * 4 + reg;
                float bd = wbuf[w].qp[il][il - jl + 63];
                float e = (ac[js][reg] + bd) * scale;
                if (i0 + w * 16 + il == j0 + jl) e = NEGMAX;
                ev[js][reg] = e * tauexp;
            }
        }

        // ---- online softmax; p single plane, l from rounded p ----
        float alpha[4], mn[4];
        #pragma unroll
        for (int reg = 0; reg < 4; ++reg) {
            float mx = fmaxf(fmaxf(ev[0][reg], ev[1][reg]),
                             fmaxf(ev[2][reg], ev[3][reg]));
            #pragma unroll
            for (int m = 1; m < 16; m <<= 1) mx = fmaxf(mx, __shfl_xor(mx, m));
            float m2 = fmaxf(m_r[reg], mx);
            alpha[reg] = __expf(m_r[reg] - m2);
            mn[reg] = m2;
            m_r[reg] = m2;
        }
        float ss[4] = {0.f, 0.f, 0.f, 0.f};
        #pragma unroll
        for (int js = 0; js < 4; ++js) {
            int jl = js * 16 + c;
            #pragma unroll
            for (int reg = 0; reg < 4; ++reg) {
                float p = __expf(ev[js][reg] - mn[reg]);
                ushort_t ph = f2bf(p);
                ss[reg] += bf2f(ph);
                wbuf[w].p[quad * 4 + reg][jl] = ph;
            }
        }
        #pragma unroll
        for (int reg = 0; reg < 4; ++reg) {
            float s = ss[reg];
            #pragma unroll
            for (int m = 1; m < 16; m <<= 1) s += __shfl_xor(s, m);
            l_r[reg] = l_r[reg] * alpha[reg] + s;
        }

        __syncthreads();                   // all waves done reading K
        // stage V^T (2 planes x 64 d-rows): 16 DMA issues, 4 per wave
        #pragma unroll
        for (int it = 0; it < 4; ++it) {
            int iss = it * 4 + w;
            int pl = iss >> 3, r0 = (iss & 7) * 8;
            int row = r0 + rql;
            const ushort_t* src = (pl ? vt_l : vt_h)
                + ((size_t)b * DD + h * DHH + row) * TT + j0 + chl * 8;
            gload16(src, &Kbuf[(pl * 64 + r0) * 64]);
        }
        __syncthreads();

        // ---- O = O*alpha + p @ V (2 products) ----
        frag16 pf0 = *(const frag16*)&wbuf[w].p[c][quad * 8];
        frag16 pf1 = *(const frag16*)&wbuf[w].p[c][32 + quad * 8];
        #pragma unroll
        for (int ds = 0; ds < 4; ++ds) {
            f32x4 acc = o_acc[ds];
            #pragma unroll
            for (int reg = 0; reg < 4; ++reg) acc[reg] *= alpha[reg];
            int vrow = ds * 16 + c;
            frag16 vh0 = *(const frag16*)&Kbuf[vrow * 64 + swz0 * 8];
            frag16 vh1 = *(const frag16*)&Kbuf[vrow * 64 + swz1 * 8];
            frag16 vl0 = *(const frag16*)&Kbuf[4096 + vrow * 64 + swz0 * 8];
            frag16 vl1 = *(const frag16*)&Kbuf[4096 + vrow * 64 + swz1 * 8];
            acc = MFMA16(pf0, vh0, acc, 0, 0, 0);
            acc = MFMA16(pf0, vl0, acc, 0, 0, 0);
            acc = MFMA16(pf1, vh1, acc, 0, 0, 0);
            acc = MFMA16(pf1, vl1, acc, 0, 0, 0);
            o_acc[ds] = acc;
        }
    }

    // ---- epilogue: normalize, split, store planes ----
    #pragma unroll
    for (int ds = 0; ds < 4; ++ds)
        #pragma unroll
        for (int reg = 0; reg < 4; ++reg) {
            int row = i0 + w * 16 + quad * 4 + reg;
            size_t idx = ((size_t)row * BB + b) * DD + h * DHH + ds * 16 + c;
            float val = o_acc[ds][reg] / l_r[reg];
            ushort_t hh = f2bf(val);
            o_h[idx] = hh;
            o_l[idx] = f2bf(val - bf2f(hh));
        }
}

// ---------------------------------------------------------------------------
// launch
// ---------------------------------------------------------------------------
extern "C" void kernel_launch(void* const* d_in, const int* in_sizes, int n_in,
                              void* d_out, int out_size, void* d_ws, size_t ws_size,
                              hipStream_t stream) {
    const float* x     = (const float*)d_in[0];
    const float* W_qkv = (const float*)d_in[1];
    const float* W_pos = (const float*)d_in[2];
    const float* pos_u = (const float*)d_in[3];
    const float* pos_v = (const float*)d_in[4];
    const float* W_out = (const float*)d_in[5];
    const float* b_out = (const float*)d_in[6];
    const float* tau   = (const float*)d_in[7];
    float* out = (float*)d_out;

    ushort_t* p = (ushort_t*)d_ws;
    ushort_t* feat_h  = p; p += 1024 * 512;
    ushort_t* feat_l  = p; p += 1024 * 512;
    ushort_t* WposT_h = p; p += 512 * 512;
    ushort_t* WposT_l = p; p += 512 * 512;
    ushort_t* table_h = p; p += 1024 * 512;
    ushort_t* x_h     = p; p += 4096 * 512;   // reused as VT_h after qkv GEMM
    ushort_t* x_l     = p; p += 4096 * 512;   // reused as VT_l
    ushort_t* WqkvT_h = p; p += 1536 * 512;
    ushort_t* WqkvT_l = p; p += 1536 * 512;
    ushort_t* qkv_h   = p; p += 4096 * 1536;
    ushort_t* qkv_l   = p; p += 4096 * 1536;
    ushort_t* WoutT_h = p; p += 512 * 512;
    ushort_t* WoutT_l = p; p += 512 * 512;
    ushort_t* ao_h    = p; p += 4096 * 512;
    ushort_t* ao_l    = p; p += 4096 * 512;
    ushort_t* vt_h = x_h;
    ushort_t* vt_l = x_l;

    // 1. input prep
    prep_kernel<<<5376, 256, 0, stream>>>(
        x, W_pos, W_qkv, W_out, feat_h, feat_l, x_h, x_l,
        WposT_h, WposT_l, WqkvT_h, WqkvT_l, WoutT_h, WoutT_l);
    // 2. qkv = x @ W_qkv
    gemm_bf3<128, 128, 1><<<dim3(12, 32), 256, 0, stream>>>(
        x_h, x_l, WqkvT_h, WqkvT_l, nullptr, nullptr, qkv_h, qkv_l,
        4096, 1536, 512);
    // 3. table GEMM (hi plane) + V transpose, fused
    l3_kernel<<<768, 256, 0, stream>>>(
        feat_h, feat_l, WposT_h, WposT_l, table_h, qkv_h, qkv_l, vt_h, vt_l);
    // 4. fused attention -> attno planes  (grid: XCD = b)
    attn_kernel<<<dim3(BB, 8, HH), 256, 0, stream>>>(
        qkv_h, qkv_l, table_h, vt_h, vt_l, pos_u, pos_v, tau, ao_h, ao_l);
    // 5. out = attno @ W_out + b_out
    gemm_bf3<64, 128, 0><<<dim3(4, 64), 256, 0, stream>>>(
        ao_h, ao_l, WoutT_h, WoutT_l, b_out, out, nullptr, nullptr,
        4096, 512, 512);
}